// Round 1
// 1599.988 us; speedup vs baseline: 1.6484x; 1.6484x over previous
//
#include <hip/hip_runtime.h>

typedef int i32x4 __attribute__((ext_vector_type(4)));

static constexpr int M_TOK = 16384;       // B*S
static constexpr int D_IN  = 2048;
static constexpr int H_FF  = 5632;
static constexpr int NW    = H_FF * D_IN; // 11534336

__device__ __forceinline__ void async16(const void* g, void* l) {
    __builtin_amdgcn_global_load_lds((__attribute__((address_space(1))) void*)g,
                                     (__attribute__((address_space(3))) void*)l,
                                     16, 0, 0);
}

// ---------------- weight abs-mean reduction, FP64 accumulate ----------------
__global__ void absum_partial(const float4* __restrict__ w, int n4, double* __restrict__ part) {
    __shared__ double s[256];
    const int t = threadIdx.x;
    double acc = 0.0;
    for (int i = blockIdx.x * 256 + t; i < n4; i += gridDim.x * 256) {
        float4 v = w[i];
        acc += fabs((double)v.x) + fabs((double)v.y) + fabs((double)v.z) + fabs((double)v.w);
    }
    s[t] = acc;
    __syncthreads();
    for (int o = 128; o > 0; o >>= 1) {
        if (t < o) s[t] += s[t + o];
        __syncthreads();
    }
    if (t == 0) part[blockIdx.x] = s[0];
}

__global__ void finalize_scales(const double* __restrict__ parts, double* __restrict__ scales,
                                int nblocks, double inv_n) {
    const int t = threadIdx.x;
    if (t < 3) {
        const double* p = parts + t * nblocks;
        double s = 0.0;
        for (int i = 0; i < nblocks; ++i) s += p[i];
        double c = fmax(s * inv_n, 1e-5);   // clip(mean|w|, EPS)
        scales[t * 2]     = 1.0 / c;        // quantization scale (fp64)
        scales[t * 2 + 1] = c;              // dequant coeff (fp64)
    }
}

// ---------------- weight ternarization (FP64 rounding decision) -> int8 {-1,0,1} ----------
__global__ void quant_w_kernel(const float4* __restrict__ w, unsigned int* __restrict__ tw,
                               const double* __restrict__ scales, int idx, int n4) {
    const double s = scales[idx * 2];
    const int stride = gridDim.x * blockDim.x;
    for (int i = blockIdx.x * blockDim.x + threadIdx.x; i < n4; i += stride) {
        float4 v = w[i];
        int q0 = (int)fmin(fmax(rint((double)v.x * s), -1.0), 1.0);
        int q1 = (int)fmin(fmax(rint((double)v.y * s), -1.0), 1.0);
        int q2 = (int)fmin(fmax(rint((double)v.z * s), -1.0), 1.0);
        int q3 = (int)fmin(fmax(rint((double)v.w * s), -1.0), 1.0);
        tw[i] = (unsigned int)((q0 & 255) | ((q1 & 255) << 8) |
                               ((q2 & 255) << 16) | ((q3 & 255) << 24));
    }
}

// ---------------- x: rmsnorm + int8 absmax quant, FP64 stats & rounding ----------------
__global__ void quant_x_kernel(const float* __restrict__ x, signed char* __restrict__ qx,
                               double* __restrict__ cx) {
    __shared__ double ssum[256];
    __shared__ float  smax[256];
    const int token = blockIdx.x;
    const int t = threadIdx.x;
    const float4* xr = (const float4*)(x + (size_t)token * D_IN);
    float4 v0 = xr[t];
    float4 v1 = xr[t + 256];
    double ss = (double)v0.x*v0.x + (double)v0.y*v0.y + (double)v0.z*v0.z + (double)v0.w*v0.w
              + (double)v1.x*v1.x + (double)v1.y*v1.y + (double)v1.z*v1.z + (double)v1.w*v1.w;
    float mx = fmaxf(fmaxf(fmaxf(fabsf(v0.x), fabsf(v0.y)), fmaxf(fabsf(v0.z), fabsf(v0.w))),
                     fmaxf(fmaxf(fabsf(v1.x), fabsf(v1.y)), fmaxf(fabsf(v1.z), fabsf(v1.w))));
    ssum[t] = ss; smax[t] = mx;
    __syncthreads();
    for (int o = 128; o > 0; o >>= 1) {
        if (t < o) { ssum[t] += ssum[t + o]; smax[t] = fmaxf(smax[t], smax[t + o]); }
        __syncthreads();
    }
    const double ms    = ssum[0] * (1.0 / (double)D_IN);
    const double r     = 1.0 / sqrt(ms + 1e-6);
    const double den   = fmax((double)smax[0] * r, 1e-5);   // clip(max|xn|, EPS)
    const double scale = 127.0 / den;
    if (t == 0) cx[token] = den * (1.0 / 127.0);

    int q0 = (int)fmin(fmax(rint(((double)v0.x * r) * scale), -128.0), 127.0);
    int q1 = (int)fmin(fmax(rint(((double)v0.y * r) * scale), -128.0), 127.0);
    int q2 = (int)fmin(fmax(rint(((double)v0.z * r) * scale), -128.0), 127.0);
    int q3 = (int)fmin(fmax(rint(((double)v0.w * r) * scale), -128.0), 127.0);
    int q4 = (int)fmin(fmax(rint(((double)v1.x * r) * scale), -128.0), 127.0);
    int q5 = (int)fmin(fmax(rint(((double)v1.y * r) * scale), -128.0), 127.0);
    int q6 = (int)fmin(fmax(rint(((double)v1.z * r) * scale), -128.0), 127.0);
    int q7 = (int)fmin(fmax(rint(((double)v1.w * r) * scale), -128.0), 127.0);
    unsigned int* qr = (unsigned int*)(qx + (size_t)token * D_IN);
    qr[t]       = (unsigned int)((q0 & 255) | ((q1 & 255) << 8) | ((q2 & 255) << 16) | ((q3 & 255) << 24));
    qr[t + 256] = (unsigned int)((q4 & 255) | ((q5 & 255) << 8) | ((q6 & 255) << 16) | ((q7 & 255) << 24));
}

// ---------------- h: rmsnorm + quant IN-PLACE per token (int8 overlay), FP64 stats --------
__global__ void quant_h_kernel(float* __restrict__ h, double* __restrict__ ch) {
    __shared__ double ssum[256];
    __shared__ float  smax[256];
    const int token = blockIdx.x;
    const int t = threadIdx.x;
    float* hr = h + (size_t)token * H_FF;
    float vals[22];                       // 5632 = 256*22
    double ss = 0.0;
    float mx = 0.f;
#pragma unroll
    for (int k = 0; k < 22; ++k) {
        float v = hr[t + 256 * k];
        vals[k] = v;
        ss += (double)v * (double)v;
        mx = fmaxf(mx, fabsf(v));
    }
    ssum[t] = ss; smax[t] = mx;
    __syncthreads();
    for (int o = 128; o > 0; o >>= 1) {
        if (t < o) { ssum[t] += ssum[t + o]; smax[t] = fmaxf(smax[t], smax[t + o]); }
        __syncthreads();
    }
    const double ms    = ssum[0] * (1.0 / (double)H_FF);
    const double r     = 1.0 / sqrt(ms + 1e-6);
    const double den   = fmax((double)smax[0] * r, 1e-5);
    const double scale = 127.0 / den;
    if (t == 0) ch[token] = den * (1.0 / 127.0);
    signed char* qr = (signed char*)hr;   // in-place overlay, same token row
#pragma unroll
    for (int k = 0; k < 22; ++k) {
        qr[t + 256 * k] =
            (signed char)(int)fmin(fmax(rint(((double)vals[k] * r) * scale), -128.0), 127.0);
    }
}

// ---------------- fused GEMM1+2, int8 MFMA (exact i32 accum), silu(gate)*up -> fp32 h -----
__global__ void __launch_bounds__(256) gemm12_kernel(
    const signed char* __restrict__ qx,
    const signed char* __restrict__ tw1,
    const signed char* __restrict__ tw2,
    const double* __restrict__ cx,
    const double* __restrict__ scales,
    float* __restrict__ h)
{
    __shared__ __attribute__((aligned(16))) signed char ldsA [128 * 64];
    __shared__ __attribute__((aligned(16))) signed char ldsB1[128 * 64];
    __shared__ __attribute__((aligned(16))) signed char ldsB2[128 * 64];

    const int t  = threadIdx.x;
    const int bn = blockIdx.x;
    const int bm = blockIdx.y;

    const int srow = t >> 2;            // 64 rows per staging pass
    const int scol = (t & 3) << 4;      // 16-byte columns
    const signed char* gA  = qx  + (size_t)(bm * 128 + srow) * D_IN + scol;
    const signed char* gB1 = tw1 + (size_t)(bn * 128 + srow) * D_IN + scol;
    const signed char* gB2 = tw2 + (size_t)(bn * 128 + srow) * D_IN + scol;
    const size_t rstep = (size_t)64 * D_IN;

    signed char* lA0  = &ldsA [t * 16];
    signed char* lA1  = &ldsA [t * 16 + 4096];
    signed char* lB10 = &ldsB1[t * 16];
    signed char* lB11 = &ldsB1[t * 16 + 4096];
    signed char* lB20 = &ldsB2[t * 16];
    signed char* lB21 = &ldsB2[t * 16 + 4096];

    const int lane = t & 63;
    const int wv = t >> 6;
    const int wm = wv & 1;
    const int wn = wv >> 1;
    const int lm = lane & 15;
    const int kg = lane >> 4;

    int aoff[4], boff[4];
#pragma unroll
    for (int i = 0; i < 4; ++i) aoff[i] = (wm * 64 + i * 16 + lm) * 64 + kg * 16;
#pragma unroll
    for (int j = 0; j < 4; ++j) boff[j] = (wn * 64 + j * 16 + lm) * 64 + kg * 16;

    const i32x4 izero = {0, 0, 0, 0};
    i32x4 acc1[4][4], acc2[4][4];
#pragma unroll
    for (int i = 0; i < 4; ++i)
#pragma unroll
        for (int j = 0; j < 4; ++j) { acc1[i][j] = izero; acc2[i][j] = izero; }

    for (int kt = 0; kt < D_IN / 64; ++kt) {
        __syncthreads();
        const int go = kt * 64;
        async16(gA  + go, lA0);  async16(gA  + rstep + go, lA1);
        async16(gB1 + go, lB10); async16(gB1 + rstep + go, lB11);
        async16(gB2 + go, lB20); async16(gB2 + rstep + go, lB21);
        __syncthreads();

        i32x4 a[4], b1[4], b2[4];
#pragma unroll
        for (int i = 0; i < 4; ++i) a[i] = *(const i32x4*)&ldsA[aoff[i]];
#pragma unroll
        for (int j = 0; j < 4; ++j) {
            b1[j] = *(const i32x4*)&ldsB1[boff[j]];
            b2[j] = *(const i32x4*)&ldsB2[boff[j]];
        }
#pragma unroll
        for (int i = 0; i < 4; ++i)
#pragma unroll
            for (int j = 0; j < 4; ++j) {
                acc1[i][j] = __builtin_amdgcn_mfma_i32_16x16x64_i8(a[i], b1[j], acc1[i][j], 0, 0, 0);
                acc2[i][j] = __builtin_amdgcn_mfma_i32_16x16x64_i8(a[i], b2[j], acc2[i][j], 0, 0, 0);
            }
    }

    // epilogue: exact int accumulators, FP64 scale products, fp32 silu
    const double cw1 = scales[1];
    const double cw2 = scales[3];
#pragma unroll
    for (int i = 0; i < 4; ++i) {
#pragma unroll
        for (int v = 0; v < 4; ++v) {
            const int row = bm * 128 + wm * 64 + i * 16 + kg * 4 + v;
            const double c  = cx[row];
            const double s1 = c * cw1, s2 = c * cw2;
            float* hp = h + (size_t)row * H_FF + bn * 128 + wn * 64 + lm;
#pragma unroll
            for (int j = 0; j < 4; ++j) {
                float g  = (float)((double)acc1[i][j][v] * s1);
                float u  = (float)((double)acc2[i][j][v] * s2);
                float sg = g / (1.0f + expf(-g));   // silu
                hp[j * 16] = sg * u;
            }
        }
    }
}

// ---------------- GEMM3: int8 h-overlay (stride 4*H_FF bytes) x ternary w3 -> fp32 out ----
__global__ void __launch_bounds__(256) gemm3_kernel(
    const signed char* __restrict__ qh,
    const signed char* __restrict__ tw3,
    const double* __restrict__ ch,
    const double* __restrict__ scales,
    float* __restrict__ out)
{
    __shared__ __attribute__((aligned(16))) signed char ldsA[128 * 64];
    __shared__ __attribute__((aligned(16))) signed char ldsB[128 * 64];

    const int t  = threadIdx.x;
    const int bn = blockIdx.x;
    const int bm = blockIdx.y;

    const int srow = t >> 2;
    const int scol = (t & 3) << 4;
    const size_t qh_stride = (size_t)4 * H_FF;   // bytes per token row (fp32 overlay)
    const signed char* gA = qh  + (size_t)(bm * 128 + srow) * qh_stride + scol;
    const signed char* gB = tw3 + (size_t)(bn * 128 + srow) * H_FF + scol;
    const size_t rstepA = (size_t)64 * qh_stride;
    const size_t rstepB = (size_t)64 * H_FF;

    signed char* lA0 = &ldsA[t * 16];
    signed char* lA1 = &ldsA[t * 16 + 4096];
    signed char* lB0 = &ldsB[t * 16];
    signed char* lB1 = &ldsB[t * 16 + 4096];

    const int lane = t & 63;
    const int wv = t >> 6;
    const int wm = wv & 1;
    const int wn = wv >> 1;
    const int lm = lane & 15;
    const int kg = lane >> 4;

    int aoff[4], boff[4];
#pragma unroll
    for (int i = 0; i < 4; ++i) aoff[i] = (wm * 64 + i * 16 + lm) * 64 + kg * 16;
#pragma unroll
    for (int j = 0; j < 4; ++j) boff[j] = (wn * 64 + j * 16 + lm) * 64 + kg * 16;

    const i32x4 izero = {0, 0, 0, 0};
    i32x4 acc[4][4];
#pragma unroll
    for (int i = 0; i < 4; ++i)
#pragma unroll
        for (int j = 0; j < 4; ++j) acc[i][j] = izero;

    for (int kt = 0; kt < H_FF / 64; ++kt) {
        __syncthreads();
        const int go = kt * 64;
        async16(gA + go, lA0); async16(gA + rstepA + go, lA1);
        async16(gB + go, lB0); async16(gB + rstepB + go, lB1);
        __syncthreads();

        i32x4 a[4], b[4];
#pragma unroll
        for (int i = 0; i < 4; ++i) a[i] = *(const i32x4*)&ldsA[aoff[i]];
#pragma unroll
        for (int j = 0; j < 4; ++j) b[j] = *(const i32x4*)&ldsB[boff[j]];
#pragma unroll
        for (int i = 0; i < 4; ++i)
#pragma unroll
            for (int j = 0; j < 4; ++j)
                acc[i][j] = __builtin_amdgcn_mfma_i32_16x16x64_i8(a[i], b[j], acc[i][j], 0, 0, 0);
    }

    const double cw3 = scales[5];
#pragma unroll
    for (int i = 0; i < 4; ++i) {
#pragma unroll
        for (int v = 0; v < 4; ++v) {
            const int row = bm * 128 + wm * 64 + i * 16 + kg * 4 + v;
            const double sc = ch[row] * cw3;
            float* op = out + (size_t)row * D_IN + bn * 128 + wn * 64 + lm;
#pragma unroll
            for (int j = 0; j < 4; ++j) op[j * 16] = (float)((double)acc[i][j][v] * sc);
        }
    }
}

// ---------------- launch ----------------
extern "C" void kernel_launch(void* const* d_in, const int* in_sizes, int n_in,
                              void* d_out, int out_size, void* d_ws, size_t ws_size,
                              hipStream_t stream) {
    const float* x  = (const float*)d_in[0];
    const float* w1 = (const float*)d_in[1];
    const float* w2 = (const float*)d_in[2];
    const float* w3 = (const float*)d_in[3];

    char* ws = (char*)d_ws;
    // workspace layout (bytes, 256-aligned); total = 437,544,960
    double*      scales = (double*)(ws + 0);           // 6 d
    double*      parts  = (double*)(ws + 256);         // 3*1024 d = 24576 B
    double*      cx     = (double*)(ws + 25088);       // 16384 d = 131072 B
    double*      ch     = (double*)(ws + 156416);      // 16384 d = 131072 B
    signed char* tw1    = (signed char*)(ws + 287744);      // 11,534,336 B
    signed char* tw2    = (signed char*)(ws + 11822336);    // 11,534,336 B
    signed char* tw3    = (signed char*)(ws + 23356928);    // 11,534,336 B
    float*       hb     = (float*)(ws + 34891520);          // 369,098,752 B (int8 qh overlays in-place)
    signed char* qx     = (signed char*)(ws + 403990528);   // 33,554,432 B

    absum_partial<<<1024, 256, 0, stream>>>((const float4*)w1, NW / 4, parts);
    absum_partial<<<1024, 256, 0, stream>>>((const float4*)w2, NW / 4, parts + 1024);
    absum_partial<<<1024, 256, 0, stream>>>((const float4*)w3, NW / 4, parts + 2048);
    finalize_scales<<<1, 64, 0, stream>>>(parts, scales, 1024, 1.0 / (double)NW);
    quant_w_kernel<<<2048, 256, 0, stream>>>((const float4*)w1, (unsigned int*)tw1, scales, 0, NW / 4);
    quant_w_kernel<<<2048, 256, 0, stream>>>((const float4*)w2, (unsigned int*)tw2, scales, 1, NW / 4);
    quant_w_kernel<<<2048, 256, 0, stream>>>((const float4*)w3, (unsigned int*)tw3, scales, 2, NW / 4);
    quant_x_kernel<<<M_TOK, 256, 0, stream>>>(x, qx, cx);
    gemm12_kernel<<<dim3(H_FF / 128, M_TOK / 128), 256, 0, stream>>>(qx, tw1, tw2, cx, scales, hb);
    quant_h_kernel<<<M_TOK, 256, 0, stream>>>(hb, ch);
    gemm3_kernel<<<dim3(D_IN / 128, M_TOK / 128), 256, 0, stream>>>((const signed char*)hb,
                                                                    tw3, ch, scales,
                                                                    (float*)d_out);
}

// Round 2
// 1114.370 us; speedup vs baseline: 2.3668x; 1.4358x over previous
//
#include <hip/hip_runtime.h>

typedef int i32x4 __attribute__((ext_vector_type(4)));

static constexpr int M_TOK = 16384;       // B*S
static constexpr int D_IN  = 2048;
static constexpr int H_FF  = 5632;
static constexpr int NW    = H_FF * D_IN; // 11534336

__device__ __forceinline__ void async16(const void* g, void* l) {
    __builtin_amdgcn_global_load_lds((__attribute__((address_space(1))) void*)g,
                                     (__attribute__((address_space(3))) void*)l,
                                     16, 0, 0);
}

// raw workgroup barrier WITHOUT the vmcnt(0)/lgkmcnt(0) drain __syncthreads emits.
// compiler-only memory fences on both sides stop LDS loads hoisting/sinking across it.
__device__ __forceinline__ void sbar() {
    asm volatile("" ::: "memory");
    __builtin_amdgcn_s_barrier();
    asm volatile("" ::: "memory");
}
__device__ __forceinline__ void wait_lgkm0() {
    asm volatile("s_waitcnt lgkmcnt(0)" ::: "memory");
    __builtin_amdgcn_sched_barrier(0);   // rule 18: keep MFMAs below the wait
}

// ---------------- weight abs-mean reduction, FP64 accumulate ----------------
__global__ void absum_partial(const float4* __restrict__ w, int n4, double* __restrict__ part) {
    __shared__ double s[256];
    const int t = threadIdx.x;
    double acc = 0.0;
    for (int i = blockIdx.x * 256 + t; i < n4; i += gridDim.x * 256) {
        float4 v = w[i];
        acc += fabs((double)v.x) + fabs((double)v.y) + fabs((double)v.z) + fabs((double)v.w);
    }
    s[t] = acc;
    __syncthreads();
    for (int o = 128; o > 0; o >>= 1) {
        if (t < o) s[t] += s[t + o];
        __syncthreads();
    }
    if (t == 0) part[blockIdx.x] = s[0];
}

__global__ void finalize_scales(const double* __restrict__ parts, double* __restrict__ scales,
                                int nblocks, double inv_n) {
    const int t = threadIdx.x;
    if (t < 3) {
        const double* p = parts + t * nblocks;
        double s = 0.0;
        for (int i = 0; i < nblocks; ++i) s += p[i];
        double c = fmax(s * inv_n, 1e-5);   // clip(mean|w|, EPS)
        scales[t * 2]     = 1.0 / c;        // quantization scale (fp64)
        scales[t * 2 + 1] = c;              // dequant coeff (fp64)
    }
}

// ---------------- weight ternarization (FP64 rounding decision) -> int8 {-1,0,1} ----------
__global__ void quant_w_kernel(const float4* __restrict__ w, unsigned int* __restrict__ tw,
                               const double* __restrict__ scales, int idx, int n4) {
    const double s = scales[idx * 2];
    const int stride = gridDim.x * blockDim.x;
    for (int i = blockIdx.x * blockDim.x + threadIdx.x; i < n4; i += stride) {
        float4 v = w[i];
        int q0 = (int)fmin(fmax(rint((double)v.x * s), -1.0), 1.0);
        int q1 = (int)fmin(fmax(rint((double)v.y * s), -1.0), 1.0);
        int q2 = (int)fmin(fmax(rint((double)v.z * s), -1.0), 1.0);
        int q3 = (int)fmin(fmax(rint((double)v.w * s), -1.0), 1.0);
        tw[i] = (unsigned int)((q0 & 255) | ((q1 & 255) << 8) |
                               ((q2 & 255) << 16) | ((q3 & 255) << 24));
    }
}

// ---------------- x: rmsnorm + int8 absmax quant, FP64 stats & rounding ----------------
__global__ void quant_x_kernel(const float* __restrict__ x, signed char* __restrict__ qx,
                               double* __restrict__ cx) {
    __shared__ double ssum[256];
    __shared__ float  smax[256];
    const int token = blockIdx.x;
    const int t = threadIdx.x;
    const float4* xr = (const float4*)(x + (size_t)token * D_IN);
    float4 v0 = xr[t];
    float4 v1 = xr[t + 256];
    double ss = (double)v0.x*v0.x + (double)v0.y*v0.y + (double)v0.z*v0.z + (double)v0.w*v0.w
              + (double)v1.x*v1.x + (double)v1.y*v1.y + (double)v1.z*v1.z + (double)v1.w*v1.w;
    float mx = fmaxf(fmaxf(fmaxf(fabsf(v0.x), fabsf(v0.y)), fmaxf(fabsf(v0.z), fabsf(v0.w))),
                     fmaxf(fmaxf(fabsf(v1.x), fabsf(v1.y)), fmaxf(fabsf(v1.z), fabsf(v1.w))));
    ssum[t] = ss; smax[t] = mx;
    __syncthreads();
    for (int o = 128; o > 0; o >>= 1) {
        if (t < o) { ssum[t] += ssum[t + o]; smax[t] = fmaxf(smax[t], smax[t + o]); }
        __syncthreads();
    }
    const double ms    = ssum[0] * (1.0 / (double)D_IN);
    const double r     = 1.0 / sqrt(ms + 1e-6);
    const double den   = fmax((double)smax[0] * r, 1e-5);   // clip(max|xn|, EPS)
    const double scale = 127.0 / den;
    if (t == 0) cx[token] = den * (1.0 / 127.0);

    int q0 = (int)fmin(fmax(rint(((double)v0.x * r) * scale), -128.0), 127.0);
    int q1 = (int)fmin(fmax(rint(((double)v0.y * r) * scale), -128.0), 127.0);
    int q2 = (int)fmin(fmax(rint(((double)v0.z * r) * scale), -128.0), 127.0);
    int q3 = (int)fmin(fmax(rint(((double)v0.w * r) * scale), -128.0), 127.0);
    int q4 = (int)fmin(fmax(rint(((double)v1.x * r) * scale), -128.0), 127.0);
    int q5 = (int)fmin(fmax(rint(((double)v1.y * r) * scale), -128.0), 127.0);
    int q6 = (int)fmin(fmax(rint(((double)v1.z * r) * scale), -128.0), 127.0);
    int q7 = (int)fmin(fmax(rint(((double)v1.w * r) * scale), -128.0), 127.0);
    unsigned int* qr = (unsigned int*)(qx + (size_t)token * D_IN);
    qr[t]       = (unsigned int)((q0 & 255) | ((q1 & 255) << 8) | ((q2 & 255) << 16) | ((q3 & 255) << 24));
    qr[t + 256] = (unsigned int)((q4 & 255) | ((q5 & 255) << 8) | ((q6 & 255) << 16) | ((q7 & 255) << 24));
}

// ---------------- h: rmsnorm + quant IN-PLACE per token (int8 overlay), FP64 stats --------
__global__ void quant_h_kernel(float* __restrict__ h, double* __restrict__ ch) {
    __shared__ double ssum[256];
    __shared__ float  smax[256];
    const int token = blockIdx.x;
    const int t = threadIdx.x;
    float* hr = h + (size_t)token * H_FF;
    float vals[22];                       // 5632 = 256*22
    double ss = 0.0;
    float mx = 0.f;
#pragma unroll
    for (int k = 0; k < 22; ++k) {
        float v = hr[t + 256 * k];
        vals[k] = v;
        ss += (double)v * (double)v;
        mx = fmaxf(mx, fabsf(v));
    }
    ssum[t] = ss; smax[t] = mx;
    __syncthreads();
    for (int o = 128; o > 0; o >>= 1) {
        if (t < o) { ssum[t] += ssum[t + o]; smax[t] = fmaxf(smax[t], smax[t + o]); }
        __syncthreads();
    }
    const double ms    = ssum[0] * (1.0 / (double)H_FF);
    const double r     = 1.0 / sqrt(ms + 1e-6);
    const double den   = fmax((double)smax[0] * r, 1e-5);
    const double scale = 127.0 / den;
    if (t == 0) ch[token] = den * (1.0 / 127.0);
    signed char* qr = (signed char*)hr;   // in-place overlay, same token row
#pragma unroll
    for (int k = 0; k < 22; ++k) {
        qr[t + 256 * k] =
            (signed char)(int)fmin(fmax(rint(((double)vals[k] * r) * scale), -128.0), 127.0);
    }
}

// ---------------- fused GEMM1+2, i8 MFMA, deep-pipelined counted-vmcnt schedule -----------
// BM=256, BN=128, BK=64, 512 threads (8 waves: 4M x 2N, 64x64 per wave per gemm).
// Triple-buffered LDS (3 x 32KB): prefetch depth 2, steady-state wait = vmcnt(4).
__global__ void __launch_bounds__(512, 2) gemm12_kernel(
    const signed char* __restrict__ qx,
    const signed char* __restrict__ tw1,
    const signed char* __restrict__ tw2,
    const double* __restrict__ cx,
    const double* __restrict__ scales,
    float* __restrict__ h)
{
    // buffer layout: A [0,16384)  B1 [16384,24576)  B2 [24576,32768)
    __shared__ __attribute__((aligned(16))) signed char lds[3][32768];

    const int t  = threadIdx.x;
    const int bn = blockIdx.x;   // 0..43
    const int bm = blockIdx.y;   // 0..63

    // staging addresses (thread t covers row t>>2, 16B column (t&3)*16)
    const int srow = t >> 2;           // 0..127
    const int scol = (t & 3) << 4;
    const signed char* gA  = qx  + (size_t)(bm * 256 + srow) * D_IN + scol;
    const signed char* gB1 = tw1 + (size_t)(bn * 128 + srow) * D_IN + scol;
    const signed char* gB2 = tw2 + (size_t)(bn * 128 + srow) * D_IN + scol;
    const size_t arstep = (size_t)128 * D_IN;
    const int l16 = t * 16;

    // fragment coords
    const int lane = t & 63;
    const int wv = t >> 6;        // 0..7
    const int wm = wv & 3;        // 4 M-waves (64 rows each)
    const int wn = wv >> 2;       // 2 N-waves (64 cols each)
    const int lm = lane & 15;
    const int kg = lane >> 4;

    int aoff[4], boff[4];
#pragma unroll
    for (int i = 0; i < 4; ++i) aoff[i] = (wm * 64 + i * 16 + lm) * 64 + kg * 16;
#pragma unroll
    for (int j = 0; j < 4; ++j) boff[j] = (wn * 64 + j * 16 + lm) * 64 + kg * 16;

    const i32x4 izero = {0, 0, 0, 0};
    i32x4 acc1[4][4], acc2[4][4];
#pragma unroll
    for (int i = 0; i < 4; ++i)
#pragma unroll
        for (int j = 0; j < 4; ++j) { acc1[i][j] = izero; acc2[i][j] = izero; }

    constexpr int NT = D_IN / 64;   // 32 K-tiles

#define STAGE_A12(buf, kt) { const int go = (kt) * 64;                       \
        async16(gA + go,          &lds[buf][l16]);                           \
        async16(gA + arstep + go, &lds[buf][l16 + 8192]); }
#define STAGE_B12(buf, kt) { const int go = (kt) * 64;                       \
        async16(gB1 + go, &lds[buf][16384 + l16]);                           \
        async16(gB2 + go, &lds[buf][24576 + l16]); }

    // prologue: stage tiles 0 and 1; wait tile 0 (4 newest outstanding = tile 1)
    STAGE_A12(0, 0); STAGE_B12(0, 0);
    STAGE_A12(1, 1); STAGE_B12(1, 1);
    asm volatile("s_waitcnt vmcnt(4)" ::: "memory");
    sbar();

    for (int kt = 0; kt < NT; ++kt) {
        const int cur = kt % 3;
        const int nxt = (kt + 2) % 3;    // == (kt-1)%3: fully consumed last tile

        // ---- phase 1: gemm1 quadrant ----
        i32x4 a[4], b[4];
#pragma unroll
        for (int i = 0; i < 4; ++i) a[i] = *(const i32x4*)&lds[cur][aoff[i]];
#pragma unroll
        for (int j = 0; j < 4; ++j) b[j] = *(const i32x4*)&lds[cur][16384 + boff[j]];
        if (kt + 2 < NT) STAGE_A12(nxt, kt + 2);
        sbar();
        wait_lgkm0();
        __builtin_amdgcn_s_setprio(1);
#pragma unroll
        for (int i = 0; i < 4; ++i)
#pragma unroll
            for (int j = 0; j < 4; ++j)
                acc1[i][j] = __builtin_amdgcn_mfma_i32_16x16x64_i8(a[i], b[j], acc1[i][j], 0, 0, 0);
        __builtin_amdgcn_s_setprio(0);
        sbar();

        // ---- phase 2: gemm2 quadrant (A reused from registers) ----
#pragma unroll
        for (int j = 0; j < 4; ++j) b[j] = *(const i32x4*)&lds[cur][24576 + boff[j]];
        if (kt + 2 < NT) STAGE_B12(nxt, kt + 2);
        sbar();
        wait_lgkm0();
        __builtin_amdgcn_s_setprio(1);
#pragma unroll
        for (int i = 0; i < 4; ++i)
#pragma unroll
            for (int j = 0; j < 4; ++j)
                acc2[i][j] = __builtin_amdgcn_mfma_i32_16x16x64_i8(a[i], b[j], acc2[i][j], 0, 0, 0);
        __builtin_amdgcn_s_setprio(0);

        // end of tile: tile kt+1 must be complete; tile kt+2's 4 loads stay in flight
        if (kt + 2 < NT)      { asm volatile("s_waitcnt vmcnt(4)" ::: "memory"); }
        else if (kt + 1 < NT) { asm volatile("s_waitcnt vmcnt(0)" ::: "memory"); }
        sbar();
    }
#undef STAGE_A12
#undef STAGE_B12

    // epilogue: exact int accumulators, FP64 scale products, fp32 silu
    const double cw1 = scales[1];
    const double cw2 = scales[3];
#pragma unroll
    for (int i = 0; i < 4; ++i) {
#pragma unroll
        for (int v = 0; v < 4; ++v) {
            const int row = bm * 256 + wm * 64 + i * 16 + kg * 4 + v;
            const double c  = cx[row];
            const double s1 = c * cw1, s2 = c * cw2;
            float* hp = h + (size_t)row * H_FF + bn * 128 + wn * 64 + lm;
#pragma unroll
            for (int j = 0; j < 4; ++j) {
                float g  = (float)((double)acc1[i][j][v] * s1);
                float u  = (float)((double)acc2[i][j][v] * s2);
                float sg = g / (1.0f + expf(-g));   // silu
                hp[j * 16] = sg * u;
            }
        }
    }
}

// ---------------- GEMM3: i8 h-overlay x ternary w3, same pipelined schedule ----------------
// BM=256, BN=256, BK=64, 512 threads (8 waves: 2M x 4N, 128x64 per wave).
__global__ void __launch_bounds__(512, 2) gemm3_kernel(
    const signed char* __restrict__ qh,
    const signed char* __restrict__ tw3,
    const double* __restrict__ ch,
    const double* __restrict__ scales,
    float* __restrict__ out)
{
    // buffer layout: A [0,16384)  B [16384,32768)
    __shared__ __attribute__((aligned(16))) signed char lds[3][32768];

    const int t  = threadIdx.x;
    const int bn = blockIdx.x;   // 0..7
    const int bm = blockIdx.y;   // 0..63

    const int srow = t >> 2;
    const int scol = (t & 3) << 4;
    const size_t qh_stride = (size_t)4 * H_FF;   // bytes per token row (fp32 overlay)
    const signed char* gA = qh  + (size_t)(bm * 256 + srow) * qh_stride + scol;
    const signed char* gB = tw3 + (size_t)(bn * 256 + srow) * H_FF + scol;
    const size_t arstep = (size_t)128 * qh_stride;
    const size_t brstep = (size_t)128 * H_FF;
    const int l16 = t * 16;

    const int lane = t & 63;
    const int wv = t >> 6;
    const int wm = wv >> 2;       // 2 M-waves (128 rows each)
    const int wn = wv & 3;        // 4 N-waves (64 cols each)
    const int lm = lane & 15;
    const int kg = lane >> 4;

    int aoff[8], boff[4];
#pragma unroll
    for (int i = 0; i < 8; ++i) aoff[i] = (wm * 128 + i * 16 + lm) * 64 + kg * 16;
#pragma unroll
    for (int j = 0; j < 4; ++j) boff[j] = (wn * 64 + j * 16 + lm) * 64 + kg * 16;

    const i32x4 izero = {0, 0, 0, 0};
    i32x4 acc[8][4];
#pragma unroll
    for (int i = 0; i < 8; ++i)
#pragma unroll
        for (int j = 0; j < 4; ++j) acc[i][j] = izero;

    constexpr int NT = H_FF / 64;   // 88 K-tiles

#define STAGE_A3(buf, kt) { const int go = (kt) * 64;                        \
        async16(gA + go,          &lds[buf][l16]);                           \
        async16(gA + arstep + go, &lds[buf][l16 + 8192]); }
#define STAGE_B3(buf, kt) { const int go = (kt) * 64;                        \
        async16(gB + go,          &lds[buf][16384 + l16]);                   \
        async16(gB + brstep + go, &lds[buf][24576 + l16]); }

    STAGE_A3(0, 0); STAGE_B3(0, 0);
    STAGE_A3(1, 1); STAGE_B3(1, 1);
    asm volatile("s_waitcnt vmcnt(4)" ::: "memory");
    sbar();

    for (int kt = 0; kt < NT; ++kt) {
        const int cur = kt % 3;
        const int nxt = (kt + 2) % 3;

        // ---- phase 1: a-frags 0..3 ----
        i32x4 a[4], b[4], a2[4];
#pragma unroll
        for (int i = 0; i < 4; ++i) a[i] = *(const i32x4*)&lds[cur][aoff[i]];
#pragma unroll
        for (int j = 0; j < 4; ++j) b[j] = *(const i32x4*)&lds[cur][16384 + boff[j]];
        if (kt + 2 < NT) STAGE_A3(nxt, kt + 2);
        sbar();
        wait_lgkm0();
        __builtin_amdgcn_s_setprio(1);
#pragma unroll
        for (int i = 0; i < 4; ++i)
#pragma unroll
            for (int j = 0; j < 4; ++j)
                acc[i][j] = __builtin_amdgcn_mfma_i32_16x16x64_i8(a[i], b[j], acc[i][j], 0, 0, 0);
        __builtin_amdgcn_s_setprio(0);
        sbar();

        // ---- phase 2: a-frags 4..7 (B reused from registers) ----
#pragma unroll
        for (int i = 0; i < 4; ++i) a2[i] = *(const i32x4*)&lds[cur][aoff[i + 4]];
        if (kt + 2 < NT) STAGE_B3(nxt, kt + 2);
        sbar();
        wait_lgkm0();
        __builtin_amdgcn_s_setprio(1);
#pragma unroll
        for (int i = 0; i < 4; ++i)
#pragma unroll
            for (int j = 0; j < 4; ++j)
                acc[i + 4][j] = __builtin_amdgcn_mfma_i32_16x16x64_i8(a2[i], b[j], acc[i + 4][j], 0, 0, 0);
        __builtin_amdgcn_s_setprio(0);

        if (kt + 2 < NT)      { asm volatile("s_waitcnt vmcnt(4)" ::: "memory"); }
        else if (kt + 1 < NT) { asm volatile("s_waitcnt vmcnt(0)" ::: "memory"); }
        sbar();
    }
#undef STAGE_A3
#undef STAGE_B3

    const double cw3 = scales[5];
#pragma unroll
    for (int i = 0; i < 8; ++i) {
#pragma unroll
        for (int v = 0; v < 4; ++v) {
            const int row = bm * 256 + wm * 128 + i * 16 + kg * 4 + v;
            const double sc = ch[row] * cw3;
            float* op = out + (size_t)row * D_IN + bn * 256 + wn * 64 + lm;
#pragma unroll
            for (int j = 0; j < 4; ++j) op[j * 16] = (float)((double)acc[i][j][v] * sc);
        }
    }
}

// ---------------- launch ----------------
extern "C" void kernel_launch(void* const* d_in, const int* in_sizes, int n_in,
                              void* d_out, int out_size, void* d_ws, size_t ws_size,
                              hipStream_t stream) {
    const float* x  = (const float*)d_in[0];
    const float* w1 = (const float*)d_in[1];
    const float* w2 = (const float*)d_in[2];
    const float* w3 = (const float*)d_in[3];

    char* ws = (char*)d_ws;
    // workspace layout (bytes, 256-aligned); total = 437,544,960
    double*      scales = (double*)(ws + 0);           // 6 d
    double*      parts  = (double*)(ws + 256);         // 3*1024 d = 24576 B
    double*      cx     = (double*)(ws + 25088);       // 16384 d = 131072 B
    double*      ch     = (double*)(ws + 156416);      // 16384 d = 131072 B
    signed char* tw1    = (signed char*)(ws + 287744);      // 11,534,336 B
    signed char* tw2    = (signed char*)(ws + 11822336);    // 11,534,336 B
    signed char* tw3    = (signed char*)(ws + 23356928);    // 11,534,336 B
    float*       hb     = (float*)(ws + 34891520);          // 369,098,752 B (int8 qh overlays in-place)
    signed char* qx     = (signed char*)(ws + 403990528);   // 33,554,432 B

    absum_partial<<<1024, 256, 0, stream>>>((const float4*)w1, NW / 4, parts);
    absum_partial<<<1024, 256, 0, stream>>>((const float4*)w2, NW / 4, parts + 1024);
    absum_partial<<<1024, 256, 0, stream>>>((const float4*)w3, NW / 4, parts + 2048);
    finalize_scales<<<1, 64, 0, stream>>>(parts, scales, 1024, 1.0 / (double)NW);
    quant_w_kernel<<<2048, 256, 0, stream>>>((const float4*)w1, (unsigned int*)tw1, scales, 0, NW / 4);
    quant_w_kernel<<<2048, 256, 0, stream>>>((const float4*)w2, (unsigned int*)tw2, scales, 1, NW / 4);
    quant_w_kernel<<<2048, 256, 0, stream>>>((const float4*)w3, (unsigned int*)tw3, scales, 2, NW / 4);
    quant_x_kernel<<<M_TOK, 256, 0, stream>>>(x, qx, cx);
    gemm12_kernel<<<dim3(H_FF / 128, M_TOK / 256), 512, 0, stream>>>(qx, tw1, tw2, cx, scales, hb);
    quant_h_kernel<<<M_TOK, 256, 0, stream>>>(hb, ch);
    gemm3_kernel<<<dim3(D_IN / 256, M_TOK / 256), 512, 0, stream>>>((const signed char*)hb,
                                                                    tw3, ch, scales,
                                                                    (float*)d_out);
}

// Round 3
// 1102.334 us; speedup vs baseline: 2.3926x; 1.0109x over previous
//
#include <hip/hip_runtime.h>

typedef int i32x4 __attribute__((ext_vector_type(4)));

static constexpr int M_TOK = 16384;       // B*S
static constexpr int D_IN  = 2048;
static constexpr int H_FF  = 5632;
static constexpr int NW    = H_FF * D_IN; // 11534336

__device__ __forceinline__ void async16(const void* g, void* l) {
    __builtin_amdgcn_global_load_lds((__attribute__((address_space(1))) void*)g,
                                     (__attribute__((address_space(3))) void*)l,
                                     16, 0, 0);
}

// raw workgroup barrier WITHOUT the vmcnt(0)/lgkmcnt(0) drain __syncthreads emits.
__device__ __forceinline__ void sbar() {
    asm volatile("" ::: "memory");
    __builtin_amdgcn_s_barrier();
    asm volatile("" ::: "memory");
}
__device__ __forceinline__ void wait_lgkm0() {
    asm volatile("s_waitcnt lgkmcnt(0)" ::: "memory");
    __builtin_amdgcn_sched_barrier(0);   // rule 18: keep MFMAs below the wait
}

// ---------------- weight abs-mean reduction, FP64 accumulate ----------------
__global__ void absum_partial(const float4* __restrict__ w, int n4, double* __restrict__ part) {
    __shared__ double s[256];
    const int t = threadIdx.x;
    double acc = 0.0;
    for (int i = blockIdx.x * 256 + t; i < n4; i += gridDim.x * 256) {
        float4 v = w[i];
        acc += fabs((double)v.x) + fabs((double)v.y) + fabs((double)v.z) + fabs((double)v.w);
    }
    s[t] = acc;
    __syncthreads();
    for (int o = 128; o > 0; o >>= 1) {
        if (t < o) s[t] += s[t + o];
        __syncthreads();
    }
    if (t == 0) part[blockIdx.x] = s[0];
}

__global__ void finalize_scales(const double* __restrict__ parts, double* __restrict__ scales,
                                int nblocks, double inv_n) {
    const int t = threadIdx.x;
    if (t < 3) {
        const double* p = parts + t * nblocks;
        double s = 0.0;
        for (int i = 0; i < nblocks; ++i) s += p[i];
        double c = fmax(s * inv_n, 1e-5);   // clip(mean|w|, EPS)
        scales[t * 2]     = 1.0 / c;        // quantization scale (fp64)
        scales[t * 2 + 1] = c;              // dequant coeff (fp64)
    }
}

// ---------------- weight ternarization (FP64 rounding decision) -> int8 {-1,0,1} ----------
__global__ void quant_w_kernel(const float4* __restrict__ w, unsigned int* __restrict__ tw,
                               const double* __restrict__ scales, int idx, int n4) {
    const double s = scales[idx * 2];
    const int stride = gridDim.x * blockDim.x;
    for (int i = blockIdx.x * blockDim.x + threadIdx.x; i < n4; i += stride) {
        float4 v = w[i];
        int q0 = (int)fmin(fmax(rint((double)v.x * s), -1.0), 1.0);
        int q1 = (int)fmin(fmax(rint((double)v.y * s), -1.0), 1.0);
        int q2 = (int)fmin(fmax(rint((double)v.z * s), -1.0), 1.0);
        int q3 = (int)fmin(fmax(rint((double)v.w * s), -1.0), 1.0);
        tw[i] = (unsigned int)((q0 & 255) | ((q1 & 255) << 8) |
                               ((q2 & 255) << 16) | ((q3 & 255) << 24));
    }
}

// ---------------- x: rmsnorm + int8 absmax quant, FP64 stats & rounding ----------------
__global__ void quant_x_kernel(const float* __restrict__ x, signed char* __restrict__ qx,
                               double* __restrict__ cx) {
    __shared__ double ssum[256];
    __shared__ float  smax[256];
    const int token = blockIdx.x;
    const int t = threadIdx.x;
    const float4* xr = (const float4*)(x + (size_t)token * D_IN);
    float4 v0 = xr[t];
    float4 v1 = xr[t + 256];
    double ss = (double)v0.x*v0.x + (double)v0.y*v0.y + (double)v0.z*v0.z + (double)v0.w*v0.w
              + (double)v1.x*v1.x + (double)v1.y*v1.y + (double)v1.z*v1.z + (double)v1.w*v1.w;
    float mx = fmaxf(fmaxf(fmaxf(fabsf(v0.x), fabsf(v0.y)), fmaxf(fabsf(v0.z), fabsf(v0.w))),
                     fmaxf(fmaxf(fabsf(v1.x), fabsf(v1.y)), fmaxf(fabsf(v1.z), fabsf(v1.w))));
    ssum[t] = ss; smax[t] = mx;
    __syncthreads();
    for (int o = 128; o > 0; o >>= 1) {
        if (t < o) { ssum[t] += ssum[t + o]; smax[t] = fmaxf(smax[t], smax[t + o]); }
        __syncthreads();
    }
    const double ms    = ssum[0] * (1.0 / (double)D_IN);
    const double r     = 1.0 / sqrt(ms + 1e-6);
    const double den   = fmax((double)smax[0] * r, 1e-5);   // clip(max|xn|, EPS)
    const double scale = 127.0 / den;
    if (t == 0) cx[token] = den * (1.0 / 127.0);

    int q0 = (int)fmin(fmax(rint(((double)v0.x * r) * scale), -128.0), 127.0);
    int q1 = (int)fmin(fmax(rint(((double)v0.y * r) * scale), -128.0), 127.0);
    int q2 = (int)fmin(fmax(rint(((double)v0.z * r) * scale), -128.0), 127.0);
    int q3 = (int)fmin(fmax(rint(((double)v0.w * r) * scale), -128.0), 127.0);
    int q4 = (int)fmin(fmax(rint(((double)v1.x * r) * scale), -128.0), 127.0);
    int q5 = (int)fmin(fmax(rint(((double)v1.y * r) * scale), -128.0), 127.0);
    int q6 = (int)fmin(fmax(rint(((double)v1.z * r) * scale), -128.0), 127.0);
    int q7 = (int)fmin(fmax(rint(((double)v1.w * r) * scale), -128.0), 127.0);
    unsigned int* qr = (unsigned int*)(qx + (size_t)token * D_IN);
    qr[t]       = (unsigned int)((q0 & 255) | ((q1 & 255) << 8) | ((q2 & 255) << 16) | ((q3 & 255) << 24));
    qr[t + 256] = (unsigned int)((q4 & 255) | ((q5 & 255) << 8) | ((q6 & 255) << 16) | ((q7 & 255) << 24));
}

// ---------------- h: rmsnorm + quant IN-PLACE per token (int8 overlay), FP64 stats --------
// vectorized: float2 loads (8B/lane), packed ushort stores (2B/lane)
__global__ void quant_h_kernel(float* __restrict__ h, double* __restrict__ ch) {
    __shared__ double ssum[256];
    __shared__ float  smax[256];
    const int token = blockIdx.x;
    const int t = threadIdx.x;
    float* hr = h + (size_t)token * H_FF;
    const float2* h2 = (const float2*)hr;
    float2 vals[11];                      // 5632 floats = 2816 float2 = 256*11
    double ss = 0.0;
    float mx = 0.f;
#pragma unroll
    for (int k = 0; k < 11; ++k) {
        float2 v = h2[t + 256 * k];
        vals[k] = v;
        ss += (double)v.x * (double)v.x + (double)v.y * (double)v.y;
        mx = fmaxf(mx, fmaxf(fabsf(v.x), fabsf(v.y)));
    }
    ssum[t] = ss; smax[t] = mx;
    __syncthreads();
    for (int o = 128; o > 0; o >>= 1) {
        if (t < o) { ssum[t] += ssum[t + o]; smax[t] = fmaxf(smax[t], smax[t + o]); }
        __syncthreads();
    }
    const double ms    = ssum[0] * (1.0 / (double)H_FF);
    const double r     = 1.0 / sqrt(ms + 1e-6);
    const double den   = fmax((double)smax[0] * r, 1e-5);
    const double scale = 127.0 / den;
    if (t == 0) ch[token] = den * (1.0 / 127.0);
    unsigned short* qr = (unsigned short*)hr;   // in-place overlay, same token row
#pragma unroll
    for (int k = 0; k < 11; ++k) {
        int a = (int)fmin(fmax(rint(((double)vals[k].x * r) * scale), -128.0), 127.0);
        int b = (int)fmin(fmax(rint(((double)vals[k].y * r) * scale), -128.0), 127.0);
        qr[t + 256 * k] = (unsigned short)((a & 255) | ((b & 255) << 8));
    }
}

// LDS tile geometry (both GEMMs): rows of 64 bytes, 16B slots XOR-swizzled by (row>>1)&3
// to kill the 64B-row-stride bank conflict on ds_read_b128 (lanes lm, lm+2 were 32 banks
// apart -> 4x serialization, SQ_LDS_BANK_CONFLICT 3.46e7). Writer side: global_load_lds
// writes linearly, so the permutation is applied to the GLOBAL source slot (rule 21:
// inverse-swizzled source + swizzled read, same involution).

// ---------------- fused GEMM1+2, i8 MFMA, deep-pipelined counted-vmcnt schedule -----------
// BM=256, BN=128, BK=64, 512 threads (8 waves: 4M x 2N, 64x64 per wave per gemm).
// Triple-buffered LDS (3 x 32KB): prefetch depth 2, steady-state wait = vmcnt(4).
// Grid: 1D 2816, XCD-chunked (352/XCD), bm-fastest decode -> B panels L2-resident per XCD.
__global__ void __launch_bounds__(512, 2) gemm12_kernel(
    const signed char* __restrict__ qx,
    const signed char* __restrict__ tw1,
    const signed char* __restrict__ tw2,
    const double* __restrict__ cx,
    const double* __restrict__ scales,
    float* __restrict__ h)
{
    // buffer layout: A [0,16384)  B1 [16384,24576)  B2 [24576,32768)
    __shared__ __attribute__((aligned(16))) signed char lds[3][32768];

    const int t = threadIdx.x;
    // XCD-aware bijective swizzle: nwg=2816, 352 per XCD; bm fastest within chunk
    const int swz = (blockIdx.x & 7) * 352 + (blockIdx.x >> 3);
    const int bm  = swz & 63;    // 0..63
    const int bn  = swz >> 6;    // 0..43

    // staging: thread t covers row t>>2, swizzled 16B slot within the 64B chunk
    const int srow = t >> 2;           // 0..127
    const int scol = (((t & 3) ^ ((t >> 3) & 3)) << 4);
    const signed char* gA  = qx  + (size_t)(bm * 256 + srow) * D_IN + scol;
    const signed char* gB1 = tw1 + (size_t)(bn * 128 + srow) * D_IN + scol;
    const signed char* gB2 = tw2 + (size_t)(bn * 128 + srow) * D_IN + scol;
    const size_t arstep = (size_t)128 * D_IN;
    const int l16 = t * 16;

    // fragment coords
    const int lane = t & 63;
    const int wv = t >> 6;        // 0..7
    const int wm = wv & 3;        // 4 M-waves (64 rows each)
    const int wn = wv >> 2;       // 2 N-waves (64 cols each)
    const int lm = lane & 15;
    const int kg = lane >> 4;
    const int koff = ((kg ^ ((lm >> 1) & 3)) << 4);   // swizzled read slot (lane-constant)

    int aoff[4], boff[4];
#pragma unroll
    for (int i = 0; i < 4; ++i) aoff[i] = (wm * 64 + i * 16 + lm) * 64 + koff;
#pragma unroll
    for (int j = 0; j < 4; ++j) boff[j] = (wn * 64 + j * 16 + lm) * 64 + koff;

    const i32x4 izero = {0, 0, 0, 0};
    i32x4 acc1[4][4], acc2[4][4];
#pragma unroll
    for (int i = 0; i < 4; ++i)
#pragma unroll
        for (int j = 0; j < 4; ++j) { acc1[i][j] = izero; acc2[i][j] = izero; }

    constexpr int NT = D_IN / 64;   // 32 K-tiles

#define STAGE_A12(buf, kt) { const int go = (kt) * 64;                       \
        async16(gA + go,          &lds[buf][l16]);                           \
        async16(gA + arstep + go, &lds[buf][l16 + 8192]); }
#define STAGE_B12(buf, kt) { const int go = (kt) * 64;                       \
        async16(gB1 + go, &lds[buf][16384 + l16]);                           \
        async16(gB2 + go, &lds[buf][24576 + l16]); }

    // prologue: stage tiles 0 and 1; wait tile 0 (4 newest outstanding = tile 1)
    STAGE_A12(0, 0); STAGE_B12(0, 0);
    STAGE_A12(1, 1); STAGE_B12(1, 1);
    asm volatile("s_waitcnt vmcnt(4)" ::: "memory");
    sbar();

    for (int kt = 0; kt < NT; ++kt) {
        const int cur = kt % 3;
        const int nxt = (kt + 2) % 3;    // == (kt-1)%3: fully consumed last tile

        // ---- phase 1: gemm1 quadrant ----
        i32x4 a[4], b[4];
#pragma unroll
        for (int i = 0; i < 4; ++i) a[i] = *(const i32x4*)&lds[cur][aoff[i]];
#pragma unroll
        for (int j = 0; j < 4; ++j) b[j] = *(const i32x4*)&lds[cur][16384 + boff[j]];
        if (kt + 2 < NT) STAGE_A12(nxt, kt + 2);
        sbar();
        wait_lgkm0();
        __builtin_amdgcn_s_setprio(1);
#pragma unroll
        for (int i = 0; i < 4; ++i)
#pragma unroll
            for (int j = 0; j < 4; ++j)
                acc1[i][j] = __builtin_amdgcn_mfma_i32_16x16x64_i8(a[i], b[j], acc1[i][j], 0, 0, 0);
        __builtin_amdgcn_s_setprio(0);
        sbar();

        // ---- phase 2: gemm2 quadrant (A reused from registers) ----
#pragma unroll
        for (int j = 0; j < 4; ++j) b[j] = *(const i32x4*)&lds[cur][24576 + boff[j]];
        if (kt + 2 < NT) STAGE_B12(nxt, kt + 2);
        sbar();
        wait_lgkm0();
        __builtin_amdgcn_s_setprio(1);
#pragma unroll
        for (int i = 0; i < 4; ++i)
#pragma unroll
            for (int j = 0; j < 4; ++j)
                acc2[i][j] = __builtin_amdgcn_mfma_i32_16x16x64_i8(a[i], b[j], acc2[i][j], 0, 0, 0);
        __builtin_amdgcn_s_setprio(0);

        // end of tile: tile kt+1 must be complete; tile kt+2's 4 loads stay in flight
        if (kt + 2 < NT)      { asm volatile("s_waitcnt vmcnt(4)" ::: "memory"); }
        else if (kt + 1 < NT) { asm volatile("s_waitcnt vmcnt(0)" ::: "memory"); }
        sbar();
    }
#undef STAGE_A12
#undef STAGE_B12

    // epilogue: exact int accumulators, FP64 scale products, fp32 silu
    const double cw1 = scales[1];
    const double cw2 = scales[3];
#pragma unroll
    for (int i = 0; i < 4; ++i) {
#pragma unroll
        for (int v = 0; v < 4; ++v) {
            const int row = bm * 256 + wm * 64 + i * 16 + kg * 4 + v;
            const double c  = cx[row];
            const double s1 = c * cw1, s2 = c * cw2;
            float* hp = h + (size_t)row * H_FF + bn * 128 + wn * 64 + lm;
#pragma unroll
            for (int j = 0; j < 4; ++j) {
                float g  = (float)((double)acc1[i][j][v] * s1);
                float u  = (float)((double)acc2[i][j][v] * s2);
                float sg = g / (1.0f + expf(-g));   // silu
                hp[j * 16] = sg * u;
            }
        }
    }
}

// ---------------- GEMM3: i8 h-overlay x ternary w3, same pipelined schedule ----------------
// BM=256, BN=256, BK=64, 512 threads (8 waves: 2M x 4N, 128x64 per wave).
// Grid: 1D 512, XCD-chunked (64/XCD) -> each XCD owns one bn (B panel 1.4MB, L2-resident).
__global__ void __launch_bounds__(512, 2) gemm3_kernel(
    const signed char* __restrict__ qh,
    const signed char* __restrict__ tw3,
    const double* __restrict__ ch,
    const double* __restrict__ scales,
    float* __restrict__ out)
{
    // buffer layout: A [0,16384)  B [16384,32768)
    __shared__ __attribute__((aligned(16))) signed char lds[3][32768];

    const int t = threadIdx.x;
    const int swz = (blockIdx.x & 7) * 64 + (blockIdx.x >> 3);
    const int bm  = swz & 63;    // 0..63
    const int bn  = swz >> 6;    // 0..7

    const int srow = t >> 2;
    const int scol = (((t & 3) ^ ((t >> 3) & 3)) << 4);
    const size_t qh_stride = (size_t)4 * H_FF;   // bytes per token row (fp32 overlay)
    const signed char* gA = qh  + (size_t)(bm * 256 + srow) * qh_stride + scol;
    const signed char* gB = tw3 + (size_t)(bn * 256 + srow) * H_FF + scol;
    const size_t arstep = (size_t)128 * qh_stride;
    const size_t brstep = (size_t)128 * H_FF;
    const int l16 = t * 16;

    const int lane = t & 63;
    const int wv = t >> 6;
    const int wm = wv >> 2;       // 2 M-waves (128 rows each)
    const int wn = wv & 3;        // 4 N-waves (64 cols each)
    const int lm = lane & 15;
    const int kg = lane >> 4;
    const int koff = ((kg ^ ((lm >> 1) & 3)) << 4);

    int aoff[8], boff[4];
#pragma unroll
    for (int i = 0; i < 8; ++i) aoff[i] = (wm * 128 + i * 16 + lm) * 64 + koff;
#pragma unroll
    for (int j = 0; j < 4; ++j) boff[j] = (wn * 64 + j * 16 + lm) * 64 + koff;

    const i32x4 izero = {0, 0, 0, 0};
    i32x4 acc[8][4];
#pragma unroll
    for (int i = 0; i < 8; ++i)
#pragma unroll
        for (int j = 0; j < 4; ++j) acc[i][j] = izero;

    constexpr int NT = H_FF / 64;   // 88 K-tiles

#define STAGE_A3(buf, kt) { const int go = (kt) * 64;                        \
        async16(gA + go,          &lds[buf][l16]);                           \
        async16(gA + arstep + go, &lds[buf][l16 + 8192]); }
#define STAGE_B3(buf, kt) { const int go = (kt) * 64;                        \
        async16(gB + go,          &lds[buf][16384 + l16]);                   \
        async16(gB + brstep + go, &lds[buf][24576 + l16]); }

    STAGE_A3(0, 0); STAGE_B3(0, 0);
    STAGE_A3(1, 1); STAGE_B3(1, 1);
    asm volatile("s_waitcnt vmcnt(4)" ::: "memory");
    sbar();

    for (int kt = 0; kt < NT; ++kt) {
        const int cur = kt % 3;
        const int nxt = (kt + 2) % 3;

        // ---- phase 1: a-frags 0..3 ----
        i32x4 a[4], b[4], a2[4];
#pragma unroll
        for (int i = 0; i < 4; ++i) a[i] = *(const i32x4*)&lds[cur][aoff[i]];
#pragma unroll
        for (int j = 0; j < 4; ++j) b[j] = *(const i32x4*)&lds[cur][16384 + boff[j]];
        if (kt + 2 < NT) STAGE_A3(nxt, kt + 2);
        sbar();
        wait_lgkm0();
        __builtin_amdgcn_s_setprio(1);
#pragma unroll
        for (int i = 0; i < 4; ++i)
#pragma unroll
            for (int j = 0; j < 4; ++j)
                acc[i][j] = __builtin_amdgcn_mfma_i32_16x16x64_i8(a[i], b[j], acc[i][j], 0, 0, 0);
        __builtin_amdgcn_s_setprio(0);
        sbar();

        // ---- phase 2: a-frags 4..7 (B reused from registers) ----
#pragma unroll
        for (int i = 0; i < 4; ++i) a2[i] = *(const i32x4*)&lds[cur][aoff[i + 4]];
        if (kt + 2 < NT) STAGE_B3(nxt, kt + 2);
        sbar();
        wait_lgkm0();
        __builtin_amdgcn_s_setprio(1);
#pragma unroll
        for (int i = 0; i < 4; ++i)
#pragma unroll
            for (int j = 0; j < 4; ++j)
                acc[i + 4][j] = __builtin_amdgcn_mfma_i32_16x16x64_i8(a2[i], b[j], acc[i + 4][j], 0, 0, 0);
        __builtin_amdgcn_s_setprio(0);

        if (kt + 2 < NT)      { asm volatile("s_waitcnt vmcnt(4)" ::: "memory"); }
        else if (kt + 1 < NT) { asm volatile("s_waitcnt vmcnt(0)" ::: "memory"); }
        sbar();
    }
#undef STAGE_A3
#undef STAGE_B3

    const double cw3 = scales[5];
#pragma unroll
    for (int i = 0; i < 8; ++i) {
#pragma unroll
        for (int v = 0; v < 4; ++v) {
            const int row = bm * 256 + wm * 128 + i * 16 + kg * 4 + v;
            const double sc = ch[row] * cw3;
            float* op = out + (size_t)row * D_IN + bn * 256 + wn * 64 + lm;
#pragma unroll
            for (int j = 0; j < 4; ++j) op[j * 16] = (float)((double)acc[i][j][v] * sc);
        }
    }
}

// ---------------- launch ----------------
extern "C" void kernel_launch(void* const* d_in, const int* in_sizes, int n_in,
                              void* d_out, int out_size, void* d_ws, size_t ws_size,
                              hipStream_t stream) {
    const float* x  = (const float*)d_in[0];
    const float* w1 = (const float*)d_in[1];
    const float* w2 = (const float*)d_in[2];
    const float* w3 = (const float*)d_in[3];

    char* ws = (char*)d_ws;
    // workspace layout (bytes, 256-aligned); total = 437,544,960
    double*      scales = (double*)(ws + 0);           // 6 d
    double*      parts  = (double*)(ws + 256);         // 3*1024 d = 24576 B
    double*      cx     = (double*)(ws + 25088);       // 16384 d = 131072 B
    double*      ch     = (double*)(ws + 156416);      // 16384 d = 131072 B
    signed char* tw1    = (signed char*)(ws + 287744);      // 11,534,336 B
    signed char* tw2    = (signed char*)(ws + 11822336);    // 11,534,336 B
    signed char* tw3    = (signed char*)(ws + 23356928);    // 11,534,336 B
    float*       hb     = (float*)(ws + 34891520);          // 369,098,752 B (int8 qh overlays in-place)
    signed char* qx     = (signed char*)(ws + 403990528);   // 33,554,432 B

    absum_partial<<<1024, 256, 0, stream>>>((const float4*)w1, NW / 4, parts);
    absum_partial<<<1024, 256, 0, stream>>>((const float4*)w2, NW / 4, parts + 1024);
    absum_partial<<<1024, 256, 0, stream>>>((const float4*)w3, NW / 4, parts + 2048);
    finalize_scales<<<1, 64, 0, stream>>>(parts, scales, 1024, 1.0 / (double)NW);
    quant_w_kernel<<<2048, 256, 0, stream>>>((const float4*)w1, (unsigned int*)tw1, scales, 0, NW / 4);
    quant_w_kernel<<<2048, 256, 0, stream>>>((const float4*)w2, (unsigned int*)tw2, scales, 1, NW / 4);
    quant_w_kernel<<<2048, 256, 0, stream>>>((const float4*)w3, (unsigned int*)tw3, scales, 2, NW / 4);
    quant_x_kernel<<<M_TOK, 256, 0, stream>>>(x, qx, cx);
    gemm12_kernel<<<2816, 512, 0, stream>>>(qx, tw1, tw2, cx, scales, hb);
    quant_h_kernel<<<M_TOK, 256, 0, stream>>>(hb, ch);
    gemm3_kernel<<<512, 512, 0, stream>>>((const signed char*)hb, tw3, ch, scales, (float*)d_out);
}

// Round 4
// 1100.283 us; speedup vs baseline: 2.3971x; 1.0019x over previous
//
#include <hip/hip_runtime.h>

typedef int i32x4 __attribute__((ext_vector_type(4)));

static constexpr int M_TOK = 16384;       // B*S
static constexpr int D_IN  = 2048;
static constexpr int H_FF  = 5632;
static constexpr int NW    = H_FF * D_IN; // 11534336

__device__ __forceinline__ void async16(const void* g, void* l) {
    __builtin_amdgcn_global_load_lds((__attribute__((address_space(1))) void*)g,
                                     (__attribute__((address_space(3))) void*)l,
                                     16, 0, 0);
}

// raw workgroup barrier WITHOUT the vmcnt(0)/lgkmcnt(0) drain __syncthreads emits.
__device__ __forceinline__ void sbar() {
    asm volatile("" ::: "memory");
    __builtin_amdgcn_s_barrier();
    asm volatile("" ::: "memory");
}
// counted waits; sched_barrier(0) after lgkm keeps MFMAs below the wait (rule 18)
#define WAIT_LGKM(n) { asm volatile("s_waitcnt lgkmcnt(" #n ")" ::: "memory"); \
                       __builtin_amdgcn_sched_barrier(0); }
#define WAIT_VM(n)   { asm volatile("s_waitcnt vmcnt(" #n ")" ::: "memory"); }

// ---------------- weight abs-mean reduction, FP64 accumulate ----------------
__global__ void absum_partial(const float4* __restrict__ w, int n4, double* __restrict__ part) {
    __shared__ double s[256];
    const int t = threadIdx.x;
    double acc = 0.0;
    for (int i = blockIdx.x * 256 + t; i < n4; i += gridDim.x * 256) {
        float4 v = w[i];
        acc += fabs((double)v.x) + fabs((double)v.y) + fabs((double)v.z) + fabs((double)v.w);
    }
    s[t] = acc;
    __syncthreads();
    for (int o = 128; o > 0; o >>= 1) {
        if (t < o) s[t] += s[t + o];
        __syncthreads();
    }
    if (t == 0) part[blockIdx.x] = s[0];
}

__global__ void finalize_scales(const double* __restrict__ parts, double* __restrict__ scales,
                                int nblocks, double inv_n) {
    const int t = threadIdx.x;
    if (t < 3) {
        const double* p = parts + t * nblocks;
        double s = 0.0;
        for (int i = 0; i < nblocks; ++i) s += p[i];
        double c = fmax(s * inv_n, 1e-5);   // clip(mean|w|, EPS)
        scales[t * 2]     = 1.0 / c;        // quantization scale (fp64)
        scales[t * 2 + 1] = c;              // dequant coeff (fp64)
    }
}

// ---------------- weight ternarization (FP64 rounding decision) -> int8 {-1,0,1} ----------
__global__ void quant_w_kernel(const float4* __restrict__ w, unsigned int* __restrict__ tw,
                               const double* __restrict__ scales, int idx, int n4) {
    const double s = scales[idx * 2];
    const int stride = gridDim.x * blockDim.x;
    for (int i = blockIdx.x * blockDim.x + threadIdx.x; i < n4; i += stride) {
        float4 v = w[i];
        int q0 = (int)fmin(fmax(rint((double)v.x * s), -1.0), 1.0);
        int q1 = (int)fmin(fmax(rint((double)v.y * s), -1.0), 1.0);
        int q2 = (int)fmin(fmax(rint((double)v.z * s), -1.0), 1.0);
        int q3 = (int)fmin(fmax(rint((double)v.w * s), -1.0), 1.0);
        tw[i] = (unsigned int)((q0 & 255) | ((q1 & 255) << 8) |
                               ((q2 & 255) << 16) | ((q3 & 255) << 24));
    }
}

// ---------------- x: rmsnorm + int8 absmax quant, FP64 stats & rounding ----------------
__global__ void quant_x_kernel(const float* __restrict__ x, signed char* __restrict__ qx,
                               double* __restrict__ cx) {
    __shared__ double ssum[256];
    __shared__ float  smax[256];
    const int token = blockIdx.x;
    const int t = threadIdx.x;
    const float4* xr = (const float4*)(x + (size_t)token * D_IN);
    float4 v0 = xr[t];
    float4 v1 = xr[t + 256];
    double ss = (double)v0.x*v0.x + (double)v0.y*v0.y + (double)v0.z*v0.z + (double)v0.w*v0.w
              + (double)v1.x*v1.x + (double)v1.y*v1.y + (double)v1.z*v1.z + (double)v1.w*v1.w;
    float mx = fmaxf(fmaxf(fmaxf(fabsf(v0.x), fabsf(v0.y)), fmaxf(fabsf(v0.z), fabsf(v0.w))),
                     fmaxf(fmaxf(fabsf(v1.x), fabsf(v1.y)), fmaxf(fabsf(v1.z), fabsf(v1.w))));
    ssum[t] = ss; smax[t] = mx;
    __syncthreads();
    for (int o = 128; o > 0; o >>= 1) {
        if (t < o) { ssum[t] += ssum[t + o]; smax[t] = fmaxf(smax[t], smax[t + o]); }
        __syncthreads();
    }
    const double ms    = ssum[0] * (1.0 / (double)D_IN);
    const double r     = 1.0 / sqrt(ms + 1e-6);
    const double den   = fmax((double)smax[0] * r, 1e-5);   // clip(max|xn|, EPS)
    const double scale = 127.0 / den;
    if (t == 0) cx[token] = den * (1.0 / 127.0);

    int q0 = (int)fmin(fmax(rint(((double)v0.x * r) * scale), -128.0), 127.0);
    int q1 = (int)fmin(fmax(rint(((double)v0.y * r) * scale), -128.0), 127.0);
    int q2 = (int)fmin(fmax(rint(((double)v0.z * r) * scale), -128.0), 127.0);
    int q3 = (int)fmin(fmax(rint(((double)v0.w * r) * scale), -128.0), 127.0);
    int q4 = (int)fmin(fmax(rint(((double)v1.x * r) * scale), -128.0), 127.0);
    int q5 = (int)fmin(fmax(rint(((double)v1.y * r) * scale), -128.0), 127.0);
    int q6 = (int)fmin(fmax(rint(((double)v1.z * r) * scale), -128.0), 127.0);
    int q7 = (int)fmin(fmax(rint(((double)v1.w * r) * scale), -128.0), 127.0);
    unsigned int* qr = (unsigned int*)(qx + (size_t)token * D_IN);
    qr[t]       = (unsigned int)((q0 & 255) | ((q1 & 255) << 8) | ((q2 & 255) << 16) | ((q3 & 255) << 24));
    qr[t + 256] = (unsigned int)((q4 & 255) | ((q5 & 255) << 8) | ((q6 & 255) << 16) | ((q7 & 255) << 24));
}

// ---------------- h: rmsnorm + quant IN-PLACE per token (int8 overlay), FP64 stats --------
__global__ void quant_h_kernel(float* __restrict__ h, double* __restrict__ ch) {
    __shared__ double ssum[256];
    __shared__ float  smax[256];
    const int token = blockIdx.x;
    const int t = threadIdx.x;
    float* hr = h + (size_t)token * H_FF;
    const float2* h2 = (const float2*)hr;
    float2 vals[11];                      // 5632 floats = 2816 float2 = 256*11
    double ss = 0.0;
    float mx = 0.f;
#pragma unroll
    for (int k = 0; k < 11; ++k) {
        float2 v = h2[t + 256 * k];
        vals[k] = v;
        ss += (double)v.x * (double)v.x + (double)v.y * (double)v.y;
        mx = fmaxf(mx, fmaxf(fabsf(v.x), fabsf(v.y)));
    }
    ssum[t] = ss; smax[t] = mx;
    __syncthreads();
    for (int o = 128; o > 0; o >>= 1) {
        if (t < o) { ssum[t] += ssum[t + o]; smax[t] = fmaxf(smax[t], smax[t + o]); }
        __syncthreads();
    }
    const double ms    = ssum[0] * (1.0 / (double)H_FF);
    const double r     = 1.0 / sqrt(ms + 1e-6);
    const double den   = fmax((double)smax[0] * r, 1e-5);
    const double scale = 127.0 / den;
    if (t == 0) ch[token] = den * (1.0 / 127.0);
    unsigned short* qr = (unsigned short*)hr;   // in-place overlay, same token row
#pragma unroll
    for (int k = 0; k < 11; ++k) {
        int a = (int)fmin(fmax(rint(((double)vals[k].x * r) * scale), -128.0), 127.0);
        int b = (int)fmin(fmax(rint(((double)vals[k].y * r) * scale), -128.0), 127.0);
        qr[t + 256 * k] = (unsigned short)((a & 255) | ((b & 255) << 8));
    }
}

// LDS geometry: 64B rows, 16B slots XOR-swizzled by (row>>1)&3 (conflict-free, verified
// SQ_LDS_BANK_CONFLICT=0). 4 buffers x 32KB, prefetch depth 3, ONE barrier per K-tile:
// staging targets buf (kt+3)&3 whose prior content (tile kt-1) was fully read before the
// end-of-(kt-1) barrier (each wave's lgkmcnt(0) precedes its barrier arrival) -> safe.

// ---------------- fused GEMM1+2, i8 MFMA, 1-barrier/tile counted-wait schedule ------------
// BM=256, BN=128, BK=64, 512 threads (8 waves: 4M x 2N, 64x64 per wave per gemm).
__global__ void __launch_bounds__(512, 2) gemm12_kernel(
    const signed char* __restrict__ qx,
    const signed char* __restrict__ tw1,
    const signed char* __restrict__ tw2,
    const double* __restrict__ cx,
    const double* __restrict__ scales,
    float* __restrict__ h)
{
    // per buffer: A [0,16384)  B1 [16384,24576)  B2 [24576,32768)
    __shared__ __attribute__((aligned(16))) signed char lds[4][32768];

    const int t = threadIdx.x;
    // XCD-aware bijective swizzle: nwg=2816, 352 per XCD
    const int swz = (blockIdx.x & 7) * 352 + (blockIdx.x >> 3);
    const int bm  = swz & 63;    // 0..63
    const int bn  = swz >> 6;    // 0..43

    const int srow = t >> 2;           // 0..127
    const int scol = (((t & 3) ^ ((t >> 3) & 3)) << 4);   // inverse-swizzled global slot
    const signed char* gA  = qx  + (size_t)(bm * 256 + srow) * D_IN + scol;
    const signed char* gB1 = tw1 + (size_t)(bn * 128 + srow) * D_IN + scol;
    const signed char* gB2 = tw2 + (size_t)(bn * 128 + srow) * D_IN + scol;
    const size_t arstep = (size_t)128 * D_IN;
    const int l16 = t * 16;

    const int lane = t & 63;
    const int wv = t >> 6;        // 0..7
    const int wm = wv & 3;        // 4 M-waves (64 rows each)
    const int wn = wv >> 2;       // 2 N-waves (64 cols each)
    const int lm = lane & 15;
    const int kg = lane >> 4;
    const int koff = ((kg ^ ((lm >> 1) & 3)) << 4);   // swizzled read slot (lane-constant)

    int aoff[4], boff[4];
#pragma unroll
    for (int i = 0; i < 4; ++i) aoff[i] = (wm * 64 + i * 16 + lm) * 64 + koff;
#pragma unroll
    for (int j = 0; j < 4; ++j) boff[j] = (wn * 64 + j * 16 + lm) * 64 + koff;

    const i32x4 izero = {0, 0, 0, 0};
    i32x4 acc1[4][4], acc2[4][4];
#pragma unroll
    for (int i = 0; i < 4; ++i)
#pragma unroll
        for (int j = 0; j < 4; ++j) { acc1[i][j] = izero; acc2[i][j] = izero; }

    constexpr int NT = D_IN / 64;   // 32 K-tiles

#define STAGE12(buf, kt) { const int go = (kt) * 64;                         \
        async16(gA + go,          &lds[buf][l16]);                           \
        async16(gA + arstep + go, &lds[buf][l16 + 8192]);                    \
        async16(gB1 + go, &lds[buf][16384 + l16]);                           \
        async16(gB2 + go, &lds[buf][24576 + l16]); }

    // prologue: stage tiles 0,1,2 (12 loads); wait tile 0 (8 newest = tiles 1,2)
    STAGE12(0, 0); STAGE12(1, 1); STAGE12(2, 2);
    WAIT_VM(8);
    sbar();

    for (int kt = 0; kt < NT; ++kt) {
        const int cur = kt & 3;

        i32x4 a[4], b1[4], b2[4];
#pragma unroll
        for (int i = 0; i < 4; ++i) a[i] = *(const i32x4*)&lds[cur][aoff[i]];
#pragma unroll
        for (int j = 0; j < 4; ++j) b1[j] = *(const i32x4*)&lds[cur][16384 + boff[j]];
        __builtin_amdgcn_sched_barrier(0);   // pin issue order: (a,b1) before b2
#pragma unroll
        for (int j = 0; j < 4; ++j) b2[j] = *(const i32x4*)&lds[cur][24576 + boff[j]];
        __builtin_amdgcn_sched_barrier(0);   // pin b2 before staging
        if (kt + 3 < NT) STAGE12((kt + 3) & 3, kt + 3);

        WAIT_LGKM(4);                        // a,b1 resident; b2's 4 reads still in banks
        __builtin_amdgcn_s_setprio(1);
#pragma unroll
        for (int i = 0; i < 4; ++i)
#pragma unroll
            for (int j = 0; j < 4; ++j)
                acc1[i][j] = __builtin_amdgcn_mfma_i32_16x16x64_i8(a[i], b1[j], acc1[i][j], 0, 0, 0);
        __builtin_amdgcn_s_setprio(0);
        WAIT_LGKM(0);                        // b2 resident
        __builtin_amdgcn_s_setprio(1);
#pragma unroll
        for (int i = 0; i < 4; ++i)
#pragma unroll
            for (int j = 0; j < 4; ++j)
                acc2[i][j] = __builtin_amdgcn_mfma_i32_16x16x64_i8(a[i], b2[j], acc2[i][j], 0, 0, 0);
        __builtin_amdgcn_s_setprio(0);

        // tile kt+1 must be complete; kt+2/kt+3 (8 loads) stay in flight
        if (kt + 3 < NT)      { WAIT_VM(8); }
        else if (kt + 2 < NT) { WAIT_VM(4); }
        else if (kt + 1 < NT) { WAIT_VM(0); }
        sbar();
    }
#undef STAGE12

    // epilogue: exact int accumulators, FP64 scale products, fp32 silu
    const double cw1 = scales[1];
    const double cw2 = scales[3];
#pragma unroll
    for (int i = 0; i < 4; ++i) {
#pragma unroll
        for (int v = 0; v < 4; ++v) {
            const int row = bm * 256 + wm * 64 + i * 16 + kg * 4 + v;
            const double c  = cx[row];
            const double s1 = c * cw1, s2 = c * cw2;
            float* hp = h + (size_t)row * H_FF + bn * 128 + wn * 64 + lm;
#pragma unroll
            for (int j = 0; j < 4; ++j) {
                float g  = (float)((double)acc1[i][j][v] * s1);
                float u  = (float)((double)acc2[i][j][v] * s2);
                float sg = g / (1.0f + expf(-g));   // silu
                hp[j * 16] = sg * u;
            }
        }
    }
}

// ---------------- GEMM3: i8 h-overlay x ternary w3, same 1-barrier/tile schedule ----------
// BM=256, BN=256, BK=64, 512 threads (8 waves: 2M x 4N, 128x64 per wave).
__global__ void __launch_bounds__(512, 2) gemm3_kernel(
    const signed char* __restrict__ qh,
    const signed char* __restrict__ tw3,
    const double* __restrict__ ch,
    const double* __restrict__ scales,
    float* __restrict__ out)
{
    // per buffer: A [0,16384)  B [16384,32768)
    __shared__ __attribute__((aligned(16))) signed char lds[4][32768];

    const int t = threadIdx.x;
    const int swz = (blockIdx.x & 7) * 64 + (blockIdx.x >> 3);
    const int bm  = swz & 63;    // 0..63
    const int bn  = swz >> 6;    // 0..7

    const int srow = t >> 2;
    const int scol = (((t & 3) ^ ((t >> 3) & 3)) << 4);
    const size_t qh_stride = (size_t)4 * H_FF;   // bytes per token row (fp32 overlay)
    const signed char* gA = qh  + (size_t)(bm * 256 + srow) * qh_stride + scol;
    const signed char* gB = tw3 + (size_t)(bn * 256 + srow) * H_FF + scol;
    const size_t arstep = (size_t)128 * qh_stride;
    const size_t brstep = (size_t)128 * H_FF;
    const int l16 = t * 16;

    const int lane = t & 63;
    const int wv = t >> 6;
    const int wm = wv >> 2;       // 2 M-waves (128 rows each)
    const int wn = wv & 3;        // 4 N-waves (64 cols each)
    const int lm = lane & 15;
    const int kg = lane >> 4;
    const int koff = ((kg ^ ((lm >> 1) & 3)) << 4);

    int aoff[8], boff[4];
#pragma unroll
    for (int i = 0; i < 8; ++i) aoff[i] = (wm * 128 + i * 16 + lm) * 64 + koff;
#pragma unroll
    for (int j = 0; j < 4; ++j) boff[j] = (wn * 64 + j * 16 + lm) * 64 + koff;

    const i32x4 izero = {0, 0, 0, 0};
    i32x4 acc[8][4];
#pragma unroll
    for (int i = 0; i < 8; ++i)
#pragma unroll
        for (int j = 0; j < 4; ++j) acc[i][j] = izero;

    constexpr int NT = H_FF / 64;   // 88 K-tiles

#define STAGE3(buf, kt) { const int go = (kt) * 64;                          \
        async16(gA + go,          &lds[buf][l16]);                           \
        async16(gA + arstep + go, &lds[buf][l16 + 8192]);                    \
        async16(gB + go,          &lds[buf][16384 + l16]);                   \
        async16(gB + brstep + go, &lds[buf][24576 + l16]); }

    STAGE3(0, 0); STAGE3(1, 1); STAGE3(2, 2);
    WAIT_VM(8);
    sbar();

    for (int kt = 0; kt < NT; ++kt) {
        const int cur = kt & 3;

        i32x4 a[4], b[4], a2[4];
#pragma unroll
        for (int i = 0; i < 4; ++i) a[i] = *(const i32x4*)&lds[cur][aoff[i]];
#pragma unroll
        for (int j = 0; j < 4; ++j) b[j] = *(const i32x4*)&lds[cur][16384 + boff[j]];
        __builtin_amdgcn_sched_barrier(0);
#pragma unroll
        for (int i = 0; i < 4; ++i) a2[i] = *(const i32x4*)&lds[cur][aoff[i + 4]];
        __builtin_amdgcn_sched_barrier(0);
        if (kt + 3 < NT) STAGE3((kt + 3) & 3, kt + 3);

        WAIT_LGKM(4);                        // a,b resident; a2 in banks
        __builtin_amdgcn_s_setprio(1);
#pragma unroll
        for (int i = 0; i < 4; ++i)
#pragma unroll
            for (int j = 0; j < 4; ++j)
                acc[i][j] = __builtin_amdgcn_mfma_i32_16x16x64_i8(a[i], b[j], acc[i][j], 0, 0, 0);
        __builtin_amdgcn_s_setprio(0);
        WAIT_LGKM(0);                        // a2 resident
        __builtin_amdgcn_s_setprio(1);
#pragma unroll
        for (int i = 0; i < 4; ++i)
#pragma unroll
            for (int j = 0; j < 4; ++j)
                acc[i + 4][j] = __builtin_amdgcn_mfma_i32_16x16x64_i8(a2[i], b[j], acc[i + 4][j], 0, 0, 0);
        __builtin_amdgcn_s_setprio(0);

        if (kt + 3 < NT)      { WAIT_VM(8); }
        else if (kt + 2 < NT) { WAIT_VM(4); }
        else if (kt + 1 < NT) { WAIT_VM(0); }
        sbar();
    }
#undef STAGE3

    const double cw3 = scales[5];
#pragma unroll
    for (int i = 0; i < 8; ++i) {
#pragma unroll
        for (int v = 0; v < 4; ++v) {
            const int row = bm * 256 + wm * 128 + i * 16 + kg * 4 + v;
            const double sc = ch[row] * cw3;
            float* op = out + (size_t)row * D_IN + bn * 256 + wn * 64 + lm;
#pragma unroll
            for (int j = 0; j < 4; ++j) op[j * 16] = (float)((double)acc[i][j][v] * sc);
        }
    }
}

// ---------------- launch ----------------
extern "C" void kernel_launch(void* const* d_in, const int* in_sizes, int n_in,
                              void* d_out, int out_size, void* d_ws, size_t ws_size,
                              hipStream_t stream) {
    const float* x  = (const float*)d_in[0];
    const float* w1 = (const float*)d_in[1];
    const float* w2 = (const float*)d_in[2];
    const float* w3 = (const float*)d_in[3];

    char* ws = (char*)d_ws;
    // workspace layout (bytes, 256-aligned); total = 437,544,960
    double*      scales = (double*)(ws + 0);           // 6 d
    double*      parts  = (double*)(ws + 256);         // 3*1024 d = 24576 B
    double*      cx     = (double*)(ws + 25088);       // 16384 d = 131072 B
    double*      ch     = (double*)(ws + 156416);      // 16384 d = 131072 B
    signed char* tw1    = (signed char*)(ws + 287744);      // 11,534,336 B
    signed char* tw2    = (signed char*)(ws + 11822336);    // 11,534,336 B
    signed char* tw3    = (signed char*)(ws + 23356928);    // 11,534,336 B
    float*       hb     = (float*)(ws + 34891520);          // 369,098,752 B (int8 qh overlays in-place)
    signed char* qx     = (signed char*)(ws + 403990528);   // 33,554,432 B

    absum_partial<<<1024, 256, 0, stream>>>((const float4*)w1, NW / 4, parts);
    absum_partial<<<1024, 256, 0, stream>>>((const float4*)w2, NW / 4, parts + 1024);
    absum_partial<<<1024, 256, 0, stream>>>((const float4*)w3, NW / 4, parts + 2048);
    finalize_scales<<<1, 64, 0, stream>>>(parts, scales, 1024, 1.0 / (double)NW);
    quant_w_kernel<<<2048, 256, 0, stream>>>((const float4*)w1, (unsigned int*)tw1, scales, 0, NW / 4);
    quant_w_kernel<<<2048, 256, 0, stream>>>((const float4*)w2, (unsigned int*)tw2, scales, 1, NW / 4);
    quant_w_kernel<<<2048, 256, 0, stream>>>((const float4*)w3, (unsigned int*)tw3, scales, 2, NW / 4);
    quant_x_kernel<<<M_TOK, 256, 0, stream>>>(x, qx, cx);
    gemm12_kernel<<<2816, 512, 0, stream>>>(qx, tw1, tw2, cx, scales, hb);
    quant_h_kernel<<<M_TOK, 256, 0, stream>>>(hb, ch);
    gemm3_kernel<<<512, 512, 0, stream>>>((const signed char*)hb, tw3, ch, scales, (float*)d_out);
}

// Round 5
// 1076.803 us; speedup vs baseline: 2.4494x; 1.0218x over previous
//
#include <hip/hip_runtime.h>

typedef int i32x4 __attribute__((ext_vector_type(4)));

static constexpr int M_TOK = 16384;       // B*S
static constexpr int D_IN  = 2048;
static constexpr int H_FF  = 5632;
static constexpr int NW    = H_FF * D_IN; // 11534336

__device__ __forceinline__ void async16(const void* g, void* l) {
    __builtin_amdgcn_global_load_lds((__attribute__((address_space(1))) void*)g,
                                     (__attribute__((address_space(3))) void*)l,
                                     16, 0, 0);
}

// raw workgroup barrier WITHOUT the vmcnt(0)/lgkmcnt(0) drain __syncthreads emits.
__device__ __forceinline__ void sbar() {
    asm volatile("" ::: "memory");
    __builtin_amdgcn_s_barrier();
    asm volatile("" ::: "memory");
}
// counted waits; sched_barrier(0) after lgkm keeps dependent code below the wait (rule 18)
#define WAIT_LGKM(n) { asm volatile("s_waitcnt lgkmcnt(" #n ")" ::: "memory"); \
                       __builtin_amdgcn_sched_barrier(0); }
#define WAIT_VM(n)   { asm volatile("s_waitcnt vmcnt(" #n ")" ::: "memory"); }

// ---------------- weight abs-mean reduction, FP64 accumulate ----------------
__global__ void absum_partial(const float4* __restrict__ w, int n4, double* __restrict__ part) {
    __shared__ double s[256];
    const int t = threadIdx.x;
    double acc = 0.0;
    for (int i = blockIdx.x * 256 + t; i < n4; i += gridDim.x * 256) {
        float4 v = w[i];
        acc += fabs((double)v.x) + fabs((double)v.y) + fabs((double)v.z) + fabs((double)v.w);
    }
    s[t] = acc;
    __syncthreads();
    for (int o = 128; o > 0; o >>= 1) {
        if (t < o) s[t] += s[t + o];
        __syncthreads();
    }
    if (t == 0) part[blockIdx.x] = s[0];
}

__global__ void finalize_scales(const double* __restrict__ parts, double* __restrict__ scales,
                                int nblocks, double inv_n) {
    const int t = threadIdx.x;
    if (t < 3) {
        const double* p = parts + t * nblocks;
        double s = 0.0;
        for (int i = 0; i < nblocks; ++i) s += p[i];
        double c = fmax(s * inv_n, 1e-5);   // clip(mean|w|, EPS)
        scales[t * 2]     = 1.0 / c;        // quantization scale (fp64)
        scales[t * 2 + 1] = c;              // dequant coeff (fp64)
    }
}

// ---------------- weight ternarization (FP64 rounding decision) -> int8 {-1,0,1} ----------
__global__ void quant_w_kernel(const float4* __restrict__ w, unsigned int* __restrict__ tw,
                               const double* __restrict__ scales, int idx, int n4) {
    const double s = scales[idx * 2];
    const int stride = gridDim.x * blockDim.x;
    for (int i = blockIdx.x * blockDim.x + threadIdx.x; i < n4; i += stride) {
        float4 v = w[i];
        int q0 = (int)fmin(fmax(rint((double)v.x * s), -1.0), 1.0);
        int q1 = (int)fmin(fmax(rint((double)v.y * s), -1.0), 1.0);
        int q2 = (int)fmin(fmax(rint((double)v.z * s), -1.0), 1.0);
        int q3 = (int)fmin(fmax(rint((double)v.w * s), -1.0), 1.0);
        tw[i] = (unsigned int)((q0 & 255) | ((q1 & 255) << 8) |
                               ((q2 & 255) << 16) | ((q3 & 255) << 24));
    }
}

// ---------------- x: rmsnorm + int8 absmax quant, FP64 stats & rounding ----------------
__global__ void quant_x_kernel(const float* __restrict__ x, signed char* __restrict__ qx,
                               double* __restrict__ cx) {
    __shared__ double ssum[256];
    __shared__ float  smax[256];
    const int token = blockIdx.x;
    const int t = threadIdx.x;
    const float4* xr = (const float4*)(x + (size_t)token * D_IN);
    float4 v0 = xr[t];
    float4 v1 = xr[t + 256];
    double ss = (double)v0.x*v0.x + (double)v0.y*v0.y + (double)v0.z*v0.z + (double)v0.w*v0.w
              + (double)v1.x*v1.x + (double)v1.y*v1.y + (double)v1.z*v1.z + (double)v1.w*v1.w;
    float mx = fmaxf(fmaxf(fmaxf(fabsf(v0.x), fabsf(v0.y)), fmaxf(fabsf(v0.z), fabsf(v0.w))),
                     fmaxf(fmaxf(fabsf(v1.x), fabsf(v1.y)), fmaxf(fabsf(v1.z), fabsf(v1.w))));
    ssum[t] = ss; smax[t] = mx;
    __syncthreads();
    for (int o = 128; o > 0; o >>= 1) {
        if (t < o) { ssum[t] += ssum[t + o]; smax[t] = fmaxf(smax[t], smax[t + o]); }
        __syncthreads();
    }
    const double ms    = ssum[0] * (1.0 / (double)D_IN);
    const double r     = 1.0 / sqrt(ms + 1e-6);
    const double den   = fmax((double)smax[0] * r, 1e-5);   // clip(max|xn|, EPS)
    const double scale = 127.0 / den;
    if (t == 0) cx[token] = den * (1.0 / 127.0);

    int q0 = (int)fmin(fmax(rint(((double)v0.x * r) * scale), -128.0), 127.0);
    int q1 = (int)fmin(fmax(rint(((double)v0.y * r) * scale), -128.0), 127.0);
    int q2 = (int)fmin(fmax(rint(((double)v0.z * r) * scale), -128.0), 127.0);
    int q3 = (int)fmin(fmax(rint(((double)v0.w * r) * scale), -128.0), 127.0);
    int q4 = (int)fmin(fmax(rint(((double)v1.x * r) * scale), -128.0), 127.0);
    int q5 = (int)fmin(fmax(rint(((double)v1.y * r) * scale), -128.0), 127.0);
    int q6 = (int)fmin(fmax(rint(((double)v1.z * r) * scale), -128.0), 127.0);
    int q7 = (int)fmin(fmax(rint(((double)v1.w * r) * scale), -128.0), 127.0);
    unsigned int* qr = (unsigned int*)(qx + (size_t)token * D_IN);
    qr[t]       = (unsigned int)((q0 & 255) | ((q1 & 255) << 8) | ((q2 & 255) << 16) | ((q3 & 255) << 24));
    qr[t + 256] = (unsigned int)((q4 & 255) | ((q5 & 255) << 8) | ((q6 & 255) << 16) | ((q7 & 255) << 24));
}

// ---------------- h: rmsnorm + quant IN-PLACE per token (int8 overlay), FP64 stats --------
__global__ void quant_h_kernel(float* __restrict__ h, double* __restrict__ ch) {
    __shared__ double ssum[256];
    __shared__ float  smax[256];
    const int token = blockIdx.x;
    const int t = threadIdx.x;
    float* hr = h + (size_t)token * H_FF;
    const float2* h2 = (const float2*)hr;
    float2 vals[11];                      // 5632 floats = 2816 float2 = 256*11
    double ss = 0.0;
    float mx = 0.f;
#pragma unroll
    for (int k = 0; k < 11; ++k) {
        float2 v = h2[t + 256 * k];
        vals[k] = v;
        ss += (double)v.x * (double)v.x + (double)v.y * (double)v.y;
        mx = fmaxf(mx, fmaxf(fabsf(v.x), fabsf(v.y)));
    }
    ssum[t] = ss; smax[t] = mx;
    __syncthreads();
    for (int o = 128; o > 0; o >>= 1) {
        if (t < o) { ssum[t] += ssum[t + o]; smax[t] = fmaxf(smax[t], smax[t + o]); }
        __syncthreads();
    }
    const double ms    = ssum[0] * (1.0 / (double)H_FF);
    const double r     = 1.0 / sqrt(ms + 1e-6);
    const double den   = fmax((double)smax[0] * r, 1e-5);
    const double scale = 127.0 / den;
    if (t == 0) ch[token] = den * (1.0 / 127.0);
    unsigned short* qr = (unsigned short*)hr;   // in-place overlay, same token row
#pragma unroll
    for (int k = 0; k < 11; ++k) {
        int a = (int)fmin(fmax(rint(((double)vals[k].x * r) * scale), -128.0), 127.0);
        int b = (int)fmin(fmax(rint(((double)vals[k].y * r) * scale), -128.0), 127.0);
        qr[t + 256 * k] = (unsigned short)((a & 255) | ((b & 255) << 8));
    }
}

// LDS geometry: 64B rows, 16B slots XOR-swizzled by (row>>1)&3 (SQ_LDS_BANK_CONFLICT=0
// verified). 3 buffers x 32KB. REGISTER double-buffer of fragments: tile kt is consumed
// from regs while tile kt+1's ds_reads drain -> LDS pipe overlaps MFMA pipe (convoy fix).
// Buffer recycle proof: reads of tile kt complete (per-wave lgkm0) at end of iter kt-1;
// the sbar at iter-kt top sequences all waves past that before STAGE overwrites buf[kt%3].

// ---------------- fused GEMM1+2, i8 MFMA, reg-double-buffered pipeline --------------------
// BM=256, BN=128, BK=64, 512 threads (8 waves: 4M x 2N, 64x64 per wave per gemm).
__global__ void __launch_bounds__(512, 2) gemm12_kernel(
    const signed char* __restrict__ qx,
    const signed char* __restrict__ tw1,   // tw2 = tw1 + NW (contiguous in workspace)
    const double* __restrict__ cx,
    const double* __restrict__ scales,
    float* __restrict__ h)
{
    // per buffer: A [0,16384)  B1 [16384,24576)  B2 [24576,32768)
    __shared__ __attribute__((aligned(16))) signed char lds[3][32768];

    const int t = threadIdx.x;
    // XCD chunking (352/XCD), bn-fastest: each XCD owns a disjoint 8-slab of bm ->
    // A read once chip-wide; 32 concurrent blocks/XCD share one A-slab (L2-resident).
    const int swz = (blockIdx.x & 7) * 352 + (blockIdx.x >> 3);
    const int bm  = swz / 44;    // 0..63
    const int bn  = swz % 44;    // 0..43

    const int srow = t >> 2;           // 0..127
    const int scol = (((t & 3) ^ ((t >> 3) & 3)) << 4);   // inverse-swizzled global slot
    const signed char* gA  = qx  + (size_t)(bm * 256 + srow) * D_IN + scol;
    const signed char* gB1 = tw1 + (size_t)(bn * 128 + srow) * D_IN + scol;
    const size_t arstep = (size_t)128 * D_IN;
    const int l16 = t * 16;

    const int lane = t & 63;
    const int wv = t >> 6;        // 0..7
    const int wm = wv & 3;        // 4 M-waves (64 rows each)
    const int wn = wv >> 2;       // 2 N-waves (64 cols each)
    const int lm = lane & 15;
    const int kg = lane >> 4;
    const int koff  = ((kg ^ ((lm >> 1) & 3)) << 4);      // swizzled read slot
    const int abase = (wm * 64 + lm) * 64 + koff;         // + i*1024
    const int bbase = (wn * 64 + lm) * 64 + koff;         // + j*1024 (+16384 / +24576)

    const i32x4 izero = {0, 0, 0, 0};
    i32x4 acc1[4][4], acc2[4][4];
#pragma unroll
    for (int i = 0; i < 4; ++i)
#pragma unroll
        for (int j = 0; j < 4; ++j) { acc1[i][j] = izero; acc2[i][j] = izero; }

    i32x4 fA[12], fB[12];   // fragment double-buffer: [0..3]=A, [4..7]=B1, [8..11]=B2

    constexpr int NT = D_IN / 64;   // 32 K-tiles

#define STAGE12(buf, kt) { const int go = (kt) * 64;                         \
        async16(gA + go,           &lds[buf][l16]);                          \
        async16(gA + arstep + go,  &lds[buf][l16 + 8192]);                   \
        async16(gB1 + go,          &lds[buf][16384 + l16]);                  \
        async16(gB1 + NW + go,     &lds[buf][24576 + l16]); }
#define LOADF12(R, buf) {                                                    \
        _Pragma("unroll") for (int i = 0; i < 4; ++i)                        \
            R[i]     = *(const i32x4*)&lds[buf][abase + i * 1024];           \
        _Pragma("unroll") for (int j = 0; j < 4; ++j)                        \
            R[4 + j] = *(const i32x4*)&lds[buf][16384 + bbase + j * 1024];   \
        _Pragma("unroll") for (int j = 0; j < 4; ++j)                        \
            R[8 + j] = *(const i32x4*)&lds[buf][24576 + bbase + j * 1024]; }
#define MFMAS12(R) {                                                         \
        __builtin_amdgcn_s_setprio(1);                                       \
        _Pragma("unroll") for (int i = 0; i < 4; ++i)                        \
        _Pragma("unroll") for (int j = 0; j < 4; ++j)                        \
            acc1[i][j] = __builtin_amdgcn_mfma_i32_16x16x64_i8(R[i], R[4 + j], acc1[i][j], 0, 0, 0); \
        _Pragma("unroll") for (int i = 0; i < 4; ++i)                        \
        _Pragma("unroll") for (int j = 0; j < 4; ++j)                        \
            acc2[i][j] = __builtin_amdgcn_mfma_i32_16x16x64_i8(R[i], R[8 + j], acc2[i][j], 0, 0, 0); \
        __builtin_amdgcn_s_setprio(0); }
#define TILE12(kt, RCUR, RNXT) {                                             \
        if ((kt) + 2 < NT) { WAIT_VM(4); } else { WAIT_VM(0); }              \
        sbar();                                                              \
        if ((kt) + 3 < NT) STAGE12(((kt) % 3), (kt) + 3);                    \
        if ((kt) + 1 < NT) LOADF12(RNXT, (((kt) + 1) % 3));                  \
        __builtin_amdgcn_sched_barrier(0);                                   \
        MFMAS12(RCUR);                                                       \
        WAIT_LGKM(0); }

    // prologue: stage tiles 0,1,2; read tile 0 to regs
    STAGE12(0, 0); STAGE12(1, 1); STAGE12(2, 2);
    WAIT_VM(8); sbar();
    LOADF12(fA, 0);
    WAIT_LGKM(0);

    for (int kt = 0; kt < NT; kt += 2) {
        TILE12(kt,     fA, fB);
        TILE12(kt + 1, fB, fA);
    }
#undef STAGE12
#undef LOADF12
#undef MFMAS12
#undef TILE12

    // epilogue: exact int accumulators, FP64 scale products, fp32 silu
    const double cw1 = scales[1];
    const double cw2 = scales[3];
#pragma unroll
    for (int i = 0; i < 4; ++i) {
#pragma unroll
        for (int v = 0; v < 4; ++v) {
            const int row = bm * 256 + wm * 64 + i * 16 + kg * 4 + v;
            const double c  = cx[row];
            const double s1 = c * cw1, s2 = c * cw2;
            float* hp = h + (size_t)row * H_FF + bn * 128 + wn * 64 + lm;
#pragma unroll
            for (int j = 0; j < 4; ++j) {
                float g  = (float)((double)acc1[i][j][v] * s1);
                float u  = (float)((double)acc2[i][j][v] * s2);
                float sg = g / (1.0f + expf(-g));   // silu
                hp[j * 16] = sg * u;
            }
        }
    }
}

// ---------------- GEMM3: i8 h-overlay x ternary w3, same reg-dbuf pipeline ----------------
// BM=256, BN=256, BK=64, 512 threads (8 waves: 2M x 4N, 128x64 per wave).
__global__ void __launch_bounds__(512, 2) gemm3_kernel(
    const signed char* __restrict__ qh,
    const signed char* __restrict__ tw3,
    const double* __restrict__ ch,
    const double* __restrict__ scales,
    float* __restrict__ out)
{
    // per buffer: A [0,16384)  B [16384,32768)
    __shared__ __attribute__((aligned(16))) signed char lds[3][32768];

    const int t = threadIdx.x;
    const int swz = (blockIdx.x & 7) * 64 + (blockIdx.x >> 3);
    const int bm  = swz >> 3;    // 0..63 (disjoint 8-slab per XCD)
    const int bn  = swz & 7;     // 0..7

    const int srow = t >> 2;
    const int scol = (((t & 3) ^ ((t >> 3) & 3)) << 4);
    const size_t qh_stride = (size_t)4 * H_FF;   // bytes per token row (fp32 overlay)
    const signed char* gA = qh  + (size_t)(bm * 256 + srow) * qh_stride + scol;
    const signed char* gB = tw3 + (size_t)(bn * 256 + srow) * H_FF + scol;
    const size_t arstep = (size_t)128 * qh_stride;
    const size_t brstep = (size_t)128 * H_FF;
    const int l16 = t * 16;

    const int lane = t & 63;
    const int wv = t >> 6;
    const int wm = wv >> 2;       // 2 M-waves (128 rows each)
    const int wn = wv & 3;        // 4 N-waves (64 cols each)
    const int lm = lane & 15;
    const int kg = lane >> 4;
    const int koff  = ((kg ^ ((lm >> 1) & 3)) << 4);
    const int abase = (wm * 128 + lm) * 64 + koff;        // + i*1024, i=0..7
    const int bbase = (wn * 64 + lm) * 64 + koff;         // + j*1024 (+16384)

    const i32x4 izero = {0, 0, 0, 0};
    i32x4 acc[8][4];
#pragma unroll
    for (int i = 0; i < 8; ++i)
#pragma unroll
        for (int j = 0; j < 4; ++j) acc[i][j] = izero;

    i32x4 fA[12], fB[12];   // [0..3]=A(rows 0-63), [4..7]=B, [8..11]=A(rows 64-127)

    constexpr int NT = H_FF / 64;   // 88 K-tiles

#define STAGE3(buf, kt) { const int go = (kt) * 64;                          \
        async16(gA + go,          &lds[buf][l16]);                           \
        async16(gA + arstep + go, &lds[buf][l16 + 8192]);                    \
        async16(gB + go,          &lds[buf][16384 + l16]);                   \
        async16(gB + brstep + go, &lds[buf][24576 + l16]); }
#define LOADF3(R, buf) {                                                     \
        _Pragma("unroll") for (int i = 0; i < 4; ++i)                        \
            R[i]     = *(const i32x4*)&lds[buf][abase + i * 1024];           \
        _Pragma("unroll") for (int j = 0; j < 4; ++j)                        \
            R[4 + j] = *(const i32x4*)&lds[buf][16384 + bbase + j * 1024];   \
        _Pragma("unroll") for (int i = 0; i < 4; ++i)                        \
            R[8 + i] = *(const i32x4*)&lds[buf][abase + 4096 + i * 1024]; }
#define MFMAS3(R) {                                                          \
        __builtin_amdgcn_s_setprio(1);                                       \
        _Pragma("unroll") for (int i = 0; i < 4; ++i)                        \
        _Pragma("unroll") for (int j = 0; j < 4; ++j)                        \
            acc[i][j] = __builtin_amdgcn_mfma_i32_16x16x64_i8(R[i], R[4 + j], acc[i][j], 0, 0, 0); \
        _Pragma("unroll") for (int i = 0; i < 4; ++i)                        \
        _Pragma("unroll") for (int j = 0; j < 4; ++j)                        \
            acc[4 + i][j] = __builtin_amdgcn_mfma_i32_16x16x64_i8(R[8 + i], R[4 + j], acc[4 + i][j], 0, 0, 0); \
        __builtin_amdgcn_s_setprio(0); }
#define TILE3(kt, RCUR, RNXT) {                                              \
        if ((kt) + 2 < NT) { WAIT_VM(4); } else { WAIT_VM(0); }              \
        sbar();                                                              \
        if ((kt) + 3 < NT) STAGE3(((kt) % 3), (kt) + 3);                     \
        if ((kt) + 1 < NT) LOADF3(RNXT, (((kt) + 1) % 3));                   \
        __builtin_amdgcn_sched_barrier(0);                                   \
        MFMAS3(RCUR);                                                        \
        WAIT_LGKM(0); }

    STAGE3(0, 0); STAGE3(1, 1); STAGE3(2, 2);
    WAIT_VM(8); sbar();
    LOADF3(fA, 0);
    WAIT_LGKM(0);

    for (int kt = 0; kt < NT; kt += 2) {
        TILE3(kt,     fA, fB);
        TILE3(kt + 1, fB, fA);
    }
#undef STAGE3
#undef LOADF3
#undef MFMAS3
#undef TILE3

    const double cw3 = scales[5];
#pragma unroll
    for (int i = 0; i < 8; ++i) {
#pragma unroll
        for (int v = 0; v < 4; ++v) {
            const int row = bm * 256 + wm * 128 + i * 16 + kg * 4 + v;
            const double sc = ch[row] * cw3;
            float* op = out + (size_t)row * D_IN + bn * 256 + wn * 64 + lm;
#pragma unroll
            for (int j = 0; j < 4; ++j) op[j * 16] = (float)((double)acc[i][j][v] * sc);
        }
    }
}

// ---------------- launch ----------------
extern "C" void kernel_launch(void* const* d_in, const int* in_sizes, int n_in,
                              void* d_out, int out_size, void* d_ws, size_t ws_size,
                              hipStream_t stream) {
    const float* x  = (const float*)d_in[0];
    const float* w1 = (const float*)d_in[1];
    const float* w2 = (const float*)d_in[2];
    const float* w3 = (const float*)d_in[3];

    char* ws = (char*)d_ws;
    // workspace layout (bytes, 256-aligned); total = 437,544,960
    double*      scales = (double*)(ws + 0);           // 6 d
    double*      parts  = (double*)(ws + 256);         // 3*1024 d = 24576 B
    double*      cx     = (double*)(ws + 25088);       // 16384 d = 131072 B
    double*      ch     = (double*)(ws + 156416);      // 16384 d = 131072 B
    signed char* tw1    = (signed char*)(ws + 287744);      // 11,534,336 B
    signed char* tw2    = (signed char*)(ws + 11822080);    // = tw1 + NW (contiguous!)
    signed char* tw3    = (signed char*)(ws + 23356416);    // 11,534,336 B
    float*       hb     = (float*)(ws + 34891520);          // 369,098,752 B (int8 qh overlays in-place)
    signed char* qx     = (signed char*)(ws + 403990528);   // 33,554,432 B

    absum_partial<<<1024, 256, 0, stream>>>((const float4*)w1, NW / 4, parts);
    absum_partial<<<1024, 256, 0, stream>>>((const float4*)w2, NW / 4, parts + 1024);
    absum_partial<<<1024, 256, 0, stream>>>((const float4*)w3, NW / 4, parts + 2048);
    finalize_scales<<<1, 64, 0, stream>>>(parts, scales, 1024, 1.0 / (double)NW);
    quant_w_kernel<<<2048, 256, 0, stream>>>((const float4*)w1, (unsigned int*)tw1, scales, 0, NW / 4);
    quant_w_kernel<<<2048, 256, 0, stream>>>((const float4*)w2, (unsigned int*)tw2, scales, 1, NW / 4);
    quant_w_kernel<<<2048, 256, 0, stream>>>((const float4*)w3, (unsigned int*)tw3, scales, 2, NW / 4);
    quant_x_kernel<<<M_TOK, 256, 0, stream>>>(x, qx, cx);
    gemm12_kernel<<<2816, 512, 0, stream>>>(qx, tw1, cx, scales, hb);
    quant_h_kernel<<<M_TOK, 256, 0, stream>>>(hb, ch);
    gemm3_kernel<<<512, 512, 0, stream>>>((const signed char*)hb, tw3, ch, scales, (float*)d_out);
}